// Round 1
// baseline (2187.988 us; speedup 1.0000x reference)
//
#include <hip/hip_runtime.h>

// Problem constants (from reference)
#define N_NODES 50000
#define N_EDGES 800000
#define IN_CH   128
#define HID_CH  128
#define OUT_CH  64

// ---------------------------------------------------------------------------
// Degree count: deg[dst] += 1 per edge (float; counts are exactly representable)
__global__ __launch_bounds__(256) void count_deg_kernel(
    const int* __restrict__ dst, float* __restrict__ deg) {
  int e = blockIdx.x * 256 + threadIdx.x;
  if (e < N_EDGES) atomicAdd(&deg[dst[e]], 1.0f);
}

// deg -> dinv = rsqrt(deg + 1)
__global__ __launch_bounds__(256) void finalize_dinv_kernel(float* __restrict__ deg) {
  int n = blockIdx.x * 256 + threadIdx.x;
  if (n < N_NODES) deg[n] = rsqrtf(deg[n] + 1.0f);
}

// ---------------------------------------------------------------------------
// GEMM: out[N x C] = X[N x 128] @ W[128 x C], fp32, W staged in LDS.
// Block = 256 threads. Each thread computes 4 contiguous output cols of 1 row
// per row-group; block loops over BLOCK_ROWS rows.
template <int C, int BLOCK_ROWS>
__global__ __launch_bounds__(256) void gemm_k128_kernel(
    const float* __restrict__ X, const float* __restrict__ W,
    float* __restrict__ out, int nrows) {
  constexpr int JQ = C / 4;        // threads covering one row (32 or 16)
  constexpr int RG = 256 / JQ;     // rows per group (8 or 16)

  __shared__ float sW[128 * C];
  __shared__ float sX[RG][128];

  // Stage W into LDS (coalesced float4)
  for (int i = threadIdx.x * 4; i < 128 * C; i += 256 * 4) {
    *(float4*)&sW[i] = *(const float4*)&W[i];
  }

  const int row0 = blockIdx.x * BLOCK_ROWS;
  const int r    = threadIdx.x / JQ;
  const int j4   = (threadIdx.x % JQ) * 4;

  for (int rg = 0; rg < BLOCK_ROWS; rg += RG) {
    __syncthreads();  // protect sX from previous iteration readers
    // Stage RG rows of X: RG*32 float4 loads across 256 threads
    for (int t = threadIdx.x; t < RG * 32; t += 256) {
      int rr = t >> 5;
      int co = (t & 31) * 4;
      int grow = row0 + rg + rr;
      float4 v = make_float4(0.f, 0.f, 0.f, 0.f);
      if (grow < nrows) v = *(const float4*)&X[(long)grow * 128 + co];
      *(float4*)&sX[rr][co] = v;
    }
    __syncthreads();

    float4 acc = make_float4(0.f, 0.f, 0.f, 0.f);
#pragma unroll
    for (int k = 0; k < 128; ++k) {
      float xv = sX[r][k];
      float4 wv = *(const float4*)&sW[k * C + j4];
      acc.x = fmaf(xv, wv.x, acc.x);
      acc.y = fmaf(xv, wv.y, acc.y);
      acc.z = fmaf(xv, wv.z, acc.z);
      acc.w = fmaf(xv, wv.w, acc.w);
    }

    int grow = row0 + rg + r;
    if (grow < nrows) *(float4*)&out[(long)grow * C + j4] = acc;
  }
}

// ---------------------------------------------------------------------------
// Edge scatter: agg[dst] += hw[src] * (dinv[src]*dinv[dst]); C/4 threads/edge.
template <int C>
__global__ __launch_bounds__(256) void scatter_edges_kernel(
    const int* __restrict__ src, const int* __restrict__ dst,
    const float* __restrict__ dinv, const float* __restrict__ hw,
    float* __restrict__ agg) {
  constexpr int TPE = C / 4;  // threads per edge (32 or 16)
  int g = blockIdx.x * 256 + threadIdx.x;
  int e = g / TPE;
  if (e >= N_EDGES) return;
  int c4 = (g % TPE) * 4;
  int s = src[e];
  int d = dst[e];
  float w = dinv[s] * dinv[d];
  float4 v = *(const float4*)&hw[(long)s * C + c4];
  float* base = &agg[(long)d * C + c4];
  atomicAdd(base + 0, v.x * w);
  atomicAdd(base + 1, v.y * w);
  atomicAdd(base + 2, v.z * w);
  atomicAdd(base + 3, v.w * w);
}

// ---------------------------------------------------------------------------
// Epilogue: out = relu(agg + hw * dinv^2 + b)   (out may alias agg)
template <int C>
__global__ __launch_bounds__(256) void finish_layer_kernel(
    const float* __restrict__ agg, const float* __restrict__ hw,
    const float* __restrict__ dinv, const float* __restrict__ b,
    float* __restrict__ out) {
  int g = blockIdx.x * 256 + threadIdx.x;  // float4 index
  constexpr int Q = C / 4;
  if (g >= N_NODES * Q) return;
  int n = g / Q;
  int c4 = (g % Q) * 4;
  float di = dinv[n];
  float sn = di * di;
  float4 a = *(const float4*)&agg[(long)g * 4];
  float4 h = *(const float4*)&hw[(long)g * 4];
  float4 bb = *(const float4*)&b[c4];
  float4 o;
  o.x = fmaxf(fmaf(h.x, sn, a.x) + bb.x, 0.f);
  o.y = fmaxf(fmaf(h.y, sn, a.y) + bb.y, 0.f);
  o.z = fmaxf(fmaf(h.z, sn, a.z) + bb.z, 0.f);
  o.w = fmaxf(fmaf(h.w, sn, a.w) + bb.w, 0.f);
  *(float4*)&out[(long)g * 4] = o;
}

// ---------------------------------------------------------------------------
extern "C" void kernel_launch(void* const* d_in, const int* in_sizes, int n_in,
                              void* d_out, int out_size, void* d_ws, size_t ws_size,
                              hipStream_t stream) {
  const float* x  = (const float*)d_in[0];
  const int*   ei = (const int*)d_in[1];
  const float* W1 = (const float*)d_in[2];
  const float* b1 = (const float*)d_in[3];
  const float* W2 = (const float*)d_in[4];
  const float* b2 = (const float*)d_in[5];
  float* out = (float*)d_out;

  const int* src = ei;             // edge_index[0]
  const int* dst = ei + N_EDGES;   // edge_index[1]

  // Workspace layout (floats)
  float* ws    = (float*)d_ws;
  float* dinv  = ws;                       // N (counts, then rsqrt)
  float* hw1   = ws + 50048;               // N*128
  float* agg1  = hw1 + (size_t)N_NODES * 128;  // N*128 (becomes h1 after epilogue)
  float* hw2   = agg1 + (size_t)N_NODES * 128; // N*64

  // Zero accumulators
  hipMemsetAsync(dinv, 0, N_NODES * sizeof(float), stream);
  hipMemsetAsync(agg1, 0, (size_t)N_NODES * 128 * sizeof(float), stream);
  hipMemsetAsync(d_out, 0, (size_t)N_NODES * 64 * sizeof(float), stream);

  // Degrees -> dinv
  count_deg_kernel<<<(N_EDGES + 255) / 256, 256, 0, stream>>>(dst, dinv);
  finalize_dinv_kernel<<<(N_NODES + 255) / 256, 256, 0, stream>>>(dinv);

  // ---- Layer 1 ----
  constexpr int BR = 64;
  gemm_k128_kernel<128, BR><<<(N_NODES + BR - 1) / BR, 256, 0, stream>>>(
      x, W1, hw1, N_NODES);
  {
    long threads = (long)N_EDGES * 32;
    scatter_edges_kernel<128><<<(int)((threads + 255) / 256), 256, 0, stream>>>(
        src, dst, dinv, hw1, agg1);
  }
  {
    int q = N_NODES * 32;
    finish_layer_kernel<128><<<(q + 255) / 256, 256, 0, stream>>>(
        agg1, hw1, dinv, b1, agg1);  // in-place: agg1 becomes h1
  }

  // ---- Layer 2 ----
  gemm_k128_kernel<64, BR><<<(N_NODES + BR - 1) / BR, 256, 0, stream>>>(
      agg1, W2, hw2, N_NODES);
  {
    long threads = (long)N_EDGES * 16;
    scatter_edges_kernel<64><<<(int)((threads + 255) / 256), 256, 0, stream>>>(
        src, dst, dinv, hw2, out);
  }
  {
    int q = N_NODES * 16;
    finish_layer_kernel<64><<<(q + 255) / 256, 256, 0, stream>>>(
        out, hw2, dinv, b2, out);
  }
}

// Round 2
// 324.855 us; speedup vs baseline: 6.7353x; 6.7353x over previous
//
#include <hip/hip_runtime.h>

// Problem constants (from reference)
#define N_NODES 50000
#define N_EDGES 800000
#define IN_CH   128
#define HID_CH  128
#define OUT_CH  64

#define SCAN_B  1024
#define NB ((N_NODES + SCAN_B - 1) / SCAN_B)   // 49

// ---------------------------------------------------------------------------
// CSR build step 1: int degree histogram over dst
__global__ __launch_bounds__(256) void hist_kernel(
    const int* __restrict__ dst, int* __restrict__ deg) {
  int e = blockIdx.x * 256 + threadIdx.x;
  if (e < N_EDGES) atomicAdd(&deg[dst[e]], 1);
}

// dinv[n] = rsqrt(deg[n] + 1)  (self-loop included)
__global__ __launch_bounds__(256) void dinv_kernel(
    const int* __restrict__ deg, float* __restrict__ dinv) {
  int n = blockIdx.x * 256 + threadIdx.x;
  if (n < N_NODES) dinv[n] = rsqrtf((float)deg[n] + 1.0f);
}

// CSR build step 2a: per-chunk sums
__global__ __launch_bounds__(SCAN_B) void scan_partial_kernel(
    const int* __restrict__ deg, int* __restrict__ bsums) {
  __shared__ int sh[SCAN_B];
  int t = threadIdx.x;
  int g = blockIdx.x * SCAN_B + t;
  sh[t] = (g < N_NODES) ? deg[g] : 0;
  __syncthreads();
  for (int off = SCAN_B / 2; off > 0; off >>= 1) {
    if (t < off) sh[t] += sh[t + off];
    __syncthreads();
  }
  if (t == 0) bsums[blockIdx.x] = sh[0];
}

// CSR build step 2b: exclusive scan of the (tiny) chunk sums
__global__ __launch_bounds__(64) void scan_bsums_kernel(
    int* __restrict__ bsums, int* __restrict__ row_ptr) {
  __shared__ int sh[NB];
  int t = threadIdx.x;
  if (t < NB) sh[t] = bsums[t];
  __syncthreads();
  if (t == 0) {
    int acc = 0;
    for (int b = 0; b < NB; ++b) { int v = sh[b]; sh[b] = acc; acc += v; }
    row_ptr[N_NODES] = acc;  // == N_EDGES
  }
  __syncthreads();
  if (t < NB) bsums[t] = sh[t];
}

// CSR build step 2c: per-chunk exclusive scan + offset -> row_ptr, cursor
__global__ __launch_bounds__(SCAN_B) void scan_final_kernel(
    const int* __restrict__ deg, const int* __restrict__ bsums,
    int* __restrict__ row_ptr, int* __restrict__ cursor) {
  __shared__ int sh[SCAN_B];
  int t = threadIdx.x;
  int g = blockIdx.x * SCAN_B + t;
  int v = (g < N_NODES) ? deg[g] : 0;
  sh[t] = v;
  __syncthreads();
  for (int off = 1; off < SCAN_B; off <<= 1) {
    int add = (t >= off) ? sh[t - off] : 0;
    __syncthreads();
    sh[t] += add;
    __syncthreads();
  }
  int excl = sh[t] - v + bsums[blockIdx.x];
  if (g < N_NODES) { row_ptr[g] = excl; cursor[g] = excl; }
}

// CSR build step 3: place src ids into dst buckets
__global__ __launch_bounds__(256) void place_kernel(
    const int* __restrict__ src, const int* __restrict__ dst,
    int* __restrict__ cursor, int* __restrict__ csr_src) {
  int e = blockIdx.x * 256 + threadIdx.x;
  if (e < N_EDGES) {
    int pos = atomicAdd(&cursor[dst[e]], 1);
    csr_src[pos] = src[e];
  }
}

// ---------------------------------------------------------------------------
// GEMM: out[N x C] = X[N x 128] @ W[128 x C], fp32, W staged in LDS.
template <int C, int BLOCK_ROWS>
__global__ __launch_bounds__(256) void gemm_k128_kernel(
    const float* __restrict__ X, const float* __restrict__ W,
    float* __restrict__ out, int nrows) {
  constexpr int JQ = C / 4;        // threads covering one row (32 or 16)
  constexpr int RG = 256 / JQ;     // rows per group (8 or 16)

  __shared__ float sW[128 * C];
  __shared__ float sX[RG][128];

  for (int i = threadIdx.x * 4; i < 128 * C; i += 256 * 4) {
    *(float4*)&sW[i] = *(const float4*)&W[i];
  }

  const int row0 = blockIdx.x * BLOCK_ROWS;
  const int r    = threadIdx.x / JQ;
  const int j4   = (threadIdx.x % JQ) * 4;

  for (int rg = 0; rg < BLOCK_ROWS; rg += RG) {
    __syncthreads();
    for (int t = threadIdx.x; t < RG * 32; t += 256) {
      int rr = t >> 5;
      int co = (t & 31) * 4;
      int grow = row0 + rg + rr;
      float4 v = make_float4(0.f, 0.f, 0.f, 0.f);
      if (grow < nrows) v = *(const float4*)&X[(long)grow * 128 + co];
      *(float4*)&sX[rr][co] = v;
    }
    __syncthreads();

    float4 acc = make_float4(0.f, 0.f, 0.f, 0.f);
#pragma unroll
    for (int k = 0; k < 128; ++k) {
      float xv = sX[r][k];
      float4 wv = *(const float4*)&sW[k * C + j4];
      acc.x = fmaf(xv, wv.x, acc.x);
      acc.y = fmaf(xv, wv.y, acc.y);
      acc.z = fmaf(xv, wv.z, acc.z);
      acc.w = fmaf(xv, wv.w, acc.w);
    }

    int grow = row0 + rg + r;
    if (grow < nrows) *(float4*)&out[(long)grow * C + j4] = acc;
  }
}

// ---------------------------------------------------------------------------
// Gather aggregation, one wave per node, fused self-loop + bias + ReLU.
// C=128: each lane owns 2 channels (float2).
__global__ __launch_bounds__(256) void agg128_kernel(
    const int* __restrict__ row_ptr, const int* __restrict__ csr_src,
    const float* __restrict__ dinv, const float* __restrict__ hw,
    const float* __restrict__ bias, float* __restrict__ out) {
  int n = (blockIdx.x * 256 + threadIdx.x) >> 6;
  int lane = threadIdx.x & 63;
  if (n >= N_NODES) return;
  int c0 = lane * 2;
  float dn = dinv[n];
  int j = row_ptr[n], end = row_ptr[n + 1];
  float ax = 0.f, ay = 0.f;
  for (; j + 1 < end; j += 2) {
    int s0 = csr_src[j], s1 = csr_src[j + 1];
    float w0 = dinv[s0] * dn, w1 = dinv[s1] * dn;
    float2 v0 = *(const float2*)&hw[(long)s0 * 128 + c0];
    float2 v1 = *(const float2*)&hw[(long)s1 * 128 + c0];
    ax = fmaf(v0.x, w0, ax); ay = fmaf(v0.y, w0, ay);
    ax = fmaf(v1.x, w1, ax); ay = fmaf(v1.y, w1, ay);
  }
  if (j < end) {
    int s0 = csr_src[j];
    float w0 = dinv[s0] * dn;
    float2 v0 = *(const float2*)&hw[(long)s0 * 128 + c0];
    ax = fmaf(v0.x, w0, ax); ay = fmaf(v0.y, w0, ay);
  }
  float sn = dn * dn;
  float2 h  = *(const float2*)&hw[(long)n * 128 + c0];
  float2 bb = *(const float2*)&bias[c0];
  float ox = fmaxf(fmaf(h.x, sn, ax) + bb.x, 0.f);
  float oy = fmaxf(fmaf(h.y, sn, ay) + bb.y, 0.f);
  *(float2*)&out[(long)n * 128 + c0] = make_float2(ox, oy);
}

// C=64: each lane owns 1 channel.
__global__ __launch_bounds__(256) void agg64_kernel(
    const int* __restrict__ row_ptr, const int* __restrict__ csr_src,
    const float* __restrict__ dinv, const float* __restrict__ hw,
    const float* __restrict__ bias, float* __restrict__ out) {
  int n = (blockIdx.x * 256 + threadIdx.x) >> 6;
  int lane = threadIdx.x & 63;
  if (n >= N_NODES) return;
  float dn = dinv[n];
  int j = row_ptr[n], end = row_ptr[n + 1];
  float a = 0.f;
  for (; j + 1 < end; j += 2) {
    int s0 = csr_src[j], s1 = csr_src[j + 1];
    float w0 = dinv[s0] * dn, w1 = dinv[s1] * dn;
    float v0 = hw[(long)s0 * 64 + lane];
    float v1 = hw[(long)s1 * 64 + lane];
    a = fmaf(v0, w0, a);
    a = fmaf(v1, w1, a);
  }
  if (j < end) {
    int s0 = csr_src[j];
    float w0 = dinv[s0] * dn;
    a = fmaf(hw[(long)s0 * 64 + lane], w0, a);
  }
  float sn = dn * dn;
  float h = hw[(long)n * 64 + lane];
  float o = fmaxf(fmaf(h, sn, a) + bias[lane], 0.f);
  out[(long)n * 64 + lane] = o;
}

// ---------------------------------------------------------------------------
extern "C" void kernel_launch(void* const* d_in, const int* in_sizes, int n_in,
                              void* d_out, int out_size, void* d_ws, size_t ws_size,
                              hipStream_t stream) {
  const float* x  = (const float*)d_in[0];
  const int*   ei = (const int*)d_in[1];
  const float* W1 = (const float*)d_in[2];
  const float* b1 = (const float*)d_in[3];
  const float* W2 = (const float*)d_in[4];
  const float* b2 = (const float*)d_in[5];
  float* out = (float*)d_out;

  const int* src = ei;             // edge_index[0]
  const int* dst = ei + N_EDGES;   // edge_index[1]

  // Workspace layout (all 256B-aligned via padded counts)
  char* ws = (char*)d_ws;
  int*   deg     = (int*)ws;                         ws += 50048 * 4;   // N ints
  float* dinv    = (float*)ws;                       ws += 50048 * 4;   // N floats
  int*   row_ptr = (int*)ws;                         ws += 50048 * 4;   // N+1 ints
  int*   cursor  = (int*)ws;                         ws += 50048 * 4;   // N ints
  int*   bsums   = (int*)ws;                         ws += 64 * 4;      // NB ints
  int*   csr_src = (int*)ws;                         ws += (size_t)N_EDGES * 4;
  float* hw1     = (float*)ws;                       ws += (size_t)N_NODES * 128 * 4;
  float* h1      = (float*)ws;                       ws += (size_t)N_NODES * 128 * 4;
  float* hw2     = (float*)ws;                       ws += (size_t)N_NODES * 64 * 4;

  // ---- CSR build ----
  hipMemsetAsync(deg, 0, N_NODES * sizeof(int), stream);
  hist_kernel<<<(N_EDGES + 255) / 256, 256, 0, stream>>>(dst, deg);
  dinv_kernel<<<(N_NODES + 255) / 256, 256, 0, stream>>>(deg, dinv);
  scan_partial_kernel<<<NB, SCAN_B, 0, stream>>>(deg, bsums);
  scan_bsums_kernel<<<1, 64, 0, stream>>>(bsums, row_ptr);
  scan_final_kernel<<<NB, SCAN_B, 0, stream>>>(deg, bsums, row_ptr, cursor);
  place_kernel<<<(N_EDGES + 255) / 256, 256, 0, stream>>>(src, dst, cursor, csr_src);

  // ---- Layer 1 ----
  constexpr int BR = 64;
  gemm_k128_kernel<128, BR><<<(N_NODES + BR - 1) / BR, 256, 0, stream>>>(
      x, W1, hw1, N_NODES);
  agg128_kernel<<<(N_NODES * 64 + 255) / 256, 256, 0, stream>>>(
      row_ptr, csr_src, dinv, hw1, b1, h1);

  // ---- Layer 2 ----
  gemm_k128_kernel<64, BR><<<(N_NODES + BR - 1) / BR, 256, 0, stream>>>(
      h1, W2, hw2, N_NODES);
  agg64_kernel<<<(N_NODES * 64 + 255) / 256, 256, 0, stream>>>(
      row_ptr, csr_src, dinv, hw2, b2, out);
}

// Round 3
// 286.367 us; speedup vs baseline: 7.6405x; 1.1344x over previous
//
#include <hip/hip_runtime.h>

// Problem constants (from reference)
#define N_NODES 50000
#define N_EDGES 800000
#define IN_CH   128
#define HID_CH  128
#define OUT_CH  64

#define SCAN_B  1024
#define NB ((N_NODES + SCAN_B - 1) / SCAN_B)   // 49

// ---------------------------------------------------------------------------
// CSR build step 1: int degree histogram over dst
__global__ __launch_bounds__(256) void hist_kernel(
    const int* __restrict__ dst, int* __restrict__ deg) {
  int e = blockIdx.x * 256 + threadIdx.x;
  if (e < N_EDGES) atomicAdd(&deg[dst[e]], 1);
}

// dinv[n] = rsqrt(deg[n] + 1)  (self-loop included)
__global__ __launch_bounds__(256) void dinv_kernel(
    const int* __restrict__ deg, float* __restrict__ dinv) {
  int n = blockIdx.x * 256 + threadIdx.x;
  if (n < N_NODES) dinv[n] = rsqrtf((float)deg[n] + 1.0f);
}

// CSR build step 2a: per-chunk sums
__global__ __launch_bounds__(SCAN_B) void scan_partial_kernel(
    const int* __restrict__ deg, int* __restrict__ bsums) {
  __shared__ int sh[SCAN_B];
  int t = threadIdx.x;
  int g = blockIdx.x * SCAN_B + t;
  sh[t] = (g < N_NODES) ? deg[g] : 0;
  __syncthreads();
  for (int off = SCAN_B / 2; off > 0; off >>= 1) {
    if (t < off) sh[t] += sh[t + off];
    __syncthreads();
  }
  if (t == 0) bsums[blockIdx.x] = sh[0];
}

// CSR build step 2b: exclusive scan of the (tiny) chunk sums
__global__ __launch_bounds__(64) void scan_bsums_kernel(
    int* __restrict__ bsums, int* __restrict__ row_ptr) {
  __shared__ int sh[NB];
  int t = threadIdx.x;
  if (t < NB) sh[t] = bsums[t];
  __syncthreads();
  if (t == 0) {
    int acc = 0;
    for (int b = 0; b < NB; ++b) { int v = sh[b]; sh[b] = acc; acc += v; }
    row_ptr[N_NODES] = acc;  // == N_EDGES
  }
  __syncthreads();
  if (t < NB) bsums[t] = sh[t];
}

// CSR build step 2c: per-chunk exclusive scan + offset -> row_ptr, cursor
__global__ __launch_bounds__(SCAN_B) void scan_final_kernel(
    const int* __restrict__ deg, const int* __restrict__ bsums,
    int* __restrict__ row_ptr, int* __restrict__ cursor) {
  __shared__ int sh[SCAN_B];
  int t = threadIdx.x;
  int g = blockIdx.x * SCAN_B + t;
  int v = (g < N_NODES) ? deg[g] : 0;
  sh[t] = v;
  __syncthreads();
  for (int off = 1; off < SCAN_B; off <<= 1) {
    int add = (t >= off) ? sh[t - off] : 0;
    __syncthreads();
    sh[t] += add;
    __syncthreads();
  }
  int excl = sh[t] - v + bsums[blockIdx.x];
  if (g < N_NODES) { row_ptr[g] = excl; cursor[g] = excl; }
}

// CSR build step 3: place src ids into dst buckets
__global__ __launch_bounds__(256) void place_kernel(
    const int* __restrict__ src, const int* __restrict__ dst,
    int* __restrict__ cursor, int* __restrict__ csr_src) {
  int e = blockIdx.x * 256 + threadIdx.x;
  if (e < N_EDGES) {
    int pos = atomicAdd(&cursor[dst[e]], 1);
    csr_src[pos] = src[e];
  }
}

// ---------------------------------------------------------------------------
// GEMM: out[N x C] = X[N x 128] @ W[128 x C], fp32.
// Register tile: 4 rows x 8 cols per thread. W + X tile staged in LDS.
template <int C, int BLOCK_ROWS>
__global__ __launch_bounds__(256) void gemm_k128_kernel(
    const float* __restrict__ X, const float* __restrict__ W,
    float* __restrict__ out, int nrows) {
  constexpr int CG = C / 8;            // col groups per row: 16 (C=128) / 8 (C=64)
  constexpr int RQ = 256 / CG;         // row quads: 16 / 32
  static_assert(RQ * 4 == BLOCK_ROWS, "tile mismatch");
  constexpr int XPITCH = 132;          // pad: breaks stride-512B bank collisions

  __shared__ float sW[128 * C];
  __shared__ float sX[BLOCK_ROWS * XPITCH];

  // Stage W into LDS (coalesced float4)
  for (int i = threadIdx.x * 4; i < 128 * C; i += 1024) {
    *(float4*)&sW[i] = *(const float4*)&W[i];
  }

  const int row0 = blockIdx.x * BLOCK_ROWS;
  // Stage X tile (float4)
  for (int t = threadIdx.x; t < BLOCK_ROWS * 32; t += 256) {
    int rr = t >> 5;
    int co = (t & 31) * 4;
    int grow = row0 + rr;
    float4 v = make_float4(0.f, 0.f, 0.f, 0.f);
    if (grow < nrows) v = *(const float4*)&X[(long)grow * 128 + co];
    *(float4*)&sX[rr * XPITCH + co] = v;
  }
  __syncthreads();

  const int rq = threadIdx.x / CG;     // which row-quad
  const int cg = threadIdx.x % CG;     // which 8-col group
  const float* sXr = &sX[(rq * 4) * XPITCH];
  const float* sWc = &sW[cg * 8];

  float acc[4][8];
#pragma unroll
  for (int i = 0; i < 4; ++i)
#pragma unroll
    for (int j = 0; j < 8; ++j) acc[i][j] = 0.f;

#pragma unroll 8
  for (int k = 0; k < 128; ++k) {
    float4 wlo = *(const float4*)&sWc[k * C];
    float4 whi = *(const float4*)&sWc[k * C + 4];
    float xr[4];
    xr[0] = sXr[k];
    xr[1] = sXr[XPITCH + k];
    xr[2] = sXr[2 * XPITCH + k];
    xr[3] = sXr[3 * XPITCH + k];
#pragma unroll
    for (int i = 0; i < 4; ++i) {
      acc[i][0] = fmaf(xr[i], wlo.x, acc[i][0]);
      acc[i][1] = fmaf(xr[i], wlo.y, acc[i][1]);
      acc[i][2] = fmaf(xr[i], wlo.z, acc[i][2]);
      acc[i][3] = fmaf(xr[i], wlo.w, acc[i][3]);
      acc[i][4] = fmaf(xr[i], whi.x, acc[i][4]);
      acc[i][5] = fmaf(xr[i], whi.y, acc[i][5]);
      acc[i][6] = fmaf(xr[i], whi.z, acc[i][6]);
      acc[i][7] = fmaf(xr[i], whi.w, acc[i][7]);
    }
  }

  const int orow = row0 + rq * 4;
#pragma unroll
  for (int i = 0; i < 4; ++i) {
    if (orow + i < nrows) {
      float* o = &out[(long)(orow + i) * C + cg * 8];
      *(float4*)&o[0] = make_float4(acc[i][0], acc[i][1], acc[i][2], acc[i][3]);
      *(float4*)&o[4] = make_float4(acc[i][4], acc[i][5], acc[i][6], acc[i][7]);
    }
  }
}

// ---------------------------------------------------------------------------
// Gather aggregation, one wave per node, fused self-loop + bias + ReLU.
// Unroll-4 with pipelined index loads; dinv[n] folded out of the loop.
// C=128: each lane owns 2 channels.
__global__ __launch_bounds__(256) void agg128_kernel(
    const int* __restrict__ row_ptr, const int* __restrict__ csr_src,
    const float* __restrict__ dinv, const float* __restrict__ hw,
    const float* __restrict__ bias, float* __restrict__ out) {
  int n = (blockIdx.x * 256 + threadIdx.x) >> 6;
  int lane = threadIdx.x & 63;
  if (n >= N_NODES) return;
  int c0 = lane * 2;
  const int start = row_ptr[n], end = row_ptr[n + 1];
  float ax = 0.f, ay = 0.f;
  const int nq = (end - start) >> 2;
  int j = start;
  if (nq > 0) {
    int s0 = csr_src[j], s1 = csr_src[j + 1], s2 = csr_src[j + 2], s3 = csr_src[j + 3];
    for (int q = 0; q < nq; ++q) {
      j += 4;
      int jn = (q + 1 < nq) ? j : start;  // safe clamp on last iter
      int t0 = csr_src[jn], t1 = csr_src[jn + 1], t2 = csr_src[jn + 2], t3 = csr_src[jn + 3];
      float w0 = dinv[s0], w1 = dinv[s1], w2 = dinv[s2], w3 = dinv[s3];
      float2 v0 = *(const float2*)&hw[(long)s0 * 128 + c0];
      float2 v1 = *(const float2*)&hw[(long)s1 * 128 + c0];
      float2 v2 = *(const float2*)&hw[(long)s2 * 128 + c0];
      float2 v3 = *(const float2*)&hw[(long)s3 * 128 + c0];
      ax = fmaf(v0.x, w0, ax); ay = fmaf(v0.y, w0, ay);
      ax = fmaf(v1.x, w1, ax); ay = fmaf(v1.y, w1, ay);
      ax = fmaf(v2.x, w2, ax); ay = fmaf(v2.y, w2, ay);
      ax = fmaf(v3.x, w3, ax); ay = fmaf(v3.y, w3, ay);
      s0 = t0; s1 = t1; s2 = t2; s3 = t3;
    }
  }
  for (; j < end; ++j) {
    int s = csr_src[j];
    float w = dinv[s];
    float2 v = *(const float2*)&hw[(long)s * 128 + c0];
    ax = fmaf(v.x, w, ax); ay = fmaf(v.y, w, ay);
  }
  float dn = dinv[n];
  float sn = dn * dn;
  float2 h  = *(const float2*)&hw[(long)n * 128 + c0];
  float2 bb = *(const float2*)&bias[c0];
  float ox = fmaxf(fmaf(h.x, sn, ax * dn) + bb.x, 0.f);
  float oy = fmaxf(fmaf(h.y, sn, ay * dn) + bb.y, 0.f);
  *(float2*)&out[(long)n * 128 + c0] = make_float2(ox, oy);
}

// C=64: each lane owns 1 channel.
__global__ __launch_bounds__(256) void agg64_kernel(
    const int* __restrict__ row_ptr, const int* __restrict__ csr_src,
    const float* __restrict__ dinv, const float* __restrict__ hw,
    const float* __restrict__ bias, float* __restrict__ out) {
  int n = (blockIdx.x * 256 + threadIdx.x) >> 6;
  int lane = threadIdx.x & 63;
  if (n >= N_NODES) return;
  const int start = row_ptr[n], end = row_ptr[n + 1];
  float a = 0.f;
  const int nq = (end - start) >> 2;
  int j = start;
  if (nq > 0) {
    int s0 = csr_src[j], s1 = csr_src[j + 1], s2 = csr_src[j + 2], s3 = csr_src[j + 3];
    for (int q = 0; q < nq; ++q) {
      j += 4;
      int jn = (q + 1 < nq) ? j : start;
      int t0 = csr_src[jn], t1 = csr_src[jn + 1], t2 = csr_src[jn + 2], t3 = csr_src[jn + 3];
      float w0 = dinv[s0], w1 = dinv[s1], w2 = dinv[s2], w3 = dinv[s3];
      float v0 = hw[(long)s0 * 64 + lane];
      float v1 = hw[(long)s1 * 64 + lane];
      float v2 = hw[(long)s2 * 64 + lane];
      float v3 = hw[(long)s3 * 64 + lane];
      a = fmaf(v0, w0, a);
      a = fmaf(v1, w1, a);
      a = fmaf(v2, w2, a);
      a = fmaf(v3, w3, a);
      s0 = t0; s1 = t1; s2 = t2; s3 = t3;
    }
  }
  for (; j < end; ++j) {
    int s = csr_src[j];
    a = fmaf(hw[(long)s * 64 + lane], dinv[s], a);
  }
  float dn = dinv[n];
  float sn = dn * dn;
  float h = hw[(long)n * 64 + lane];
  float o = fmaxf(fmaf(h, sn, a * dn) + bias[lane], 0.f);
  out[(long)n * 64 + lane] = o;
}

// ---------------------------------------------------------------------------
extern "C" void kernel_launch(void* const* d_in, const int* in_sizes, int n_in,
                              void* d_out, int out_size, void* d_ws, size_t ws_size,
                              hipStream_t stream) {
  const float* x  = (const float*)d_in[0];
  const int*   ei = (const int*)d_in[1];
  const float* W1 = (const float*)d_in[2];
  const float* b1 = (const float*)d_in[3];
  const float* W2 = (const float*)d_in[4];
  const float* b2 = (const float*)d_in[5];
  float* out = (float*)d_out;

  const int* src = ei;             // edge_index[0]
  const int* dst = ei + N_EDGES;   // edge_index[1]

  // Workspace layout
  char* ws = (char*)d_ws;
  int*   deg     = (int*)ws;                         ws += 50048 * 4;
  float* dinv    = (float*)ws;                       ws += 50048 * 4;
  int*   row_ptr = (int*)ws;                         ws += 50048 * 4;
  int*   cursor  = (int*)ws;                         ws += 50048 * 4;
  int*   bsums   = (int*)ws;                         ws += 64 * 4;
  int*   csr_src = (int*)ws;                         ws += (size_t)N_EDGES * 4;
  float* hw1     = (float*)ws;                       ws += (size_t)N_NODES * 128 * 4;
  float* h1      = (float*)ws;                       ws += (size_t)N_NODES * 128 * 4;
  float* hw2     = (float*)ws;                       ws += (size_t)N_NODES * 64 * 4;

  // ---- CSR build ----
  hipMemsetAsync(deg, 0, N_NODES * sizeof(int), stream);
  hist_kernel<<<(N_EDGES + 255) / 256, 256, 0, stream>>>(dst, deg);
  dinv_kernel<<<(N_NODES + 255) / 256, 256, 0, stream>>>(deg, dinv);
  scan_partial_kernel<<<NB, SCAN_B, 0, stream>>>(deg, bsums);
  scan_bsums_kernel<<<1, 64, 0, stream>>>(bsums, row_ptr);
  scan_final_kernel<<<NB, SCAN_B, 0, stream>>>(deg, bsums, row_ptr, cursor);
  place_kernel<<<(N_EDGES + 255) / 256, 256, 0, stream>>>(src, dst, cursor, csr_src);

  // ---- Layer 1 ----
  gemm_k128_kernel<128, 64><<<(N_NODES + 63) / 64, 256, 0, stream>>>(
      x, W1, hw1, N_NODES);
  agg128_kernel<<<(N_NODES * 64 + 255) / 256, 256, 0, stream>>>(
      row_ptr, csr_src, dinv, hw1, b1, h1);

  // ---- Layer 2 ----
  gemm_k128_kernel<64, 128><<<(N_NODES + 127) / 128, 256, 0, stream>>>(
      h1, W2, hw2, N_NODES);
  agg64_kernel<<<(N_NODES * 64 + 255) / 256, 256, 0, stream>>>(
      row_ptr, csr_src, dinv, hw2, b2, out);
}

// Round 4
// 246.757 us; speedup vs baseline: 8.8670x; 1.1605x over previous
//
#include <hip/hip_runtime.h>

// Problem constants (from reference)
#define N_NODES 50000
#define N_EDGES 800000
#define IN_CH   128
#define HID_CH  128
#define OUT_CH  64

#define SCAN_B  1024
#define NB ((N_NODES + SCAN_B - 1) / SCAN_B)   // 49

// ---------------------------------------------------------------------------
// bf16 helpers (RNE)
__device__ __forceinline__ unsigned bf16rne(float f) {
  unsigned u = __float_as_uint(f);
  return (u + 0x7fffu + ((u >> 16) & 1u)) >> 16;
}
__device__ __forceinline__ unsigned pack2bf(float a, float b) {
  return bf16rne(a) | (bf16rne(b) << 16);
}
__device__ __forceinline__ float bfhi_to_f(unsigned u) {   // high ushort
  return __uint_as_float(u & 0xffff0000u);
}
__device__ __forceinline__ float bflo_to_f(unsigned u) {   // low ushort
  return __uint_as_float(u << 16);
}

// ---------------------------------------------------------------------------
// CSR build step 1: int degree histogram over dst
__global__ __launch_bounds__(256) void hist_kernel(
    const int* __restrict__ dst, int* __restrict__ deg) {
  int e = blockIdx.x * 256 + threadIdx.x;
  if (e < N_EDGES) atomicAdd(&deg[dst[e]], 1);
}

// dinv[n] = rsqrt(deg[n] + 1)  (self-loop included)
__global__ __launch_bounds__(256) void dinv_kernel(
    const int* __restrict__ deg, float* __restrict__ dinv) {
  int n = blockIdx.x * 256 + threadIdx.x;
  if (n < N_NODES) dinv[n] = rsqrtf((float)deg[n] + 1.0f);
}

// CSR build step 2a: per-chunk sums
__global__ __launch_bounds__(SCAN_B) void scan_partial_kernel(
    const int* __restrict__ deg, int* __restrict__ bsums) {
  __shared__ int sh[SCAN_B];
  int t = threadIdx.x;
  int g = blockIdx.x * SCAN_B + t;
  sh[t] = (g < N_NODES) ? deg[g] : 0;
  __syncthreads();
  for (int off = SCAN_B / 2; off > 0; off >>= 1) {
    if (t < off) sh[t] += sh[t + off];
    __syncthreads();
  }
  if (t == 0) bsums[blockIdx.x] = sh[0];
}

// CSR build step 2b: exclusive scan of the (tiny) chunk sums
__global__ __launch_bounds__(64) void scan_bsums_kernel(
    int* __restrict__ bsums, int* __restrict__ row_ptr) {
  __shared__ int sh[NB];
  int t = threadIdx.x;
  if (t < NB) sh[t] = bsums[t];
  __syncthreads();
  if (t == 0) {
    int acc = 0;
    for (int b = 0; b < NB; ++b) { int v = sh[b]; sh[b] = acc; acc += v; }
    row_ptr[N_NODES] = acc;  // == N_EDGES
  }
  __syncthreads();
  if (t < NB) bsums[t] = sh[t];
}

// CSR build step 2c: per-chunk exclusive scan + offset -> row_ptr, cursor
__global__ __launch_bounds__(SCAN_B) void scan_final_kernel(
    const int* __restrict__ deg, const int* __restrict__ bsums,
    int* __restrict__ row_ptr, int* __restrict__ cursor) {
  __shared__ int sh[SCAN_B];
  int t = threadIdx.x;
  int g = blockIdx.x * SCAN_B + t;
  int v = (g < N_NODES) ? deg[g] : 0;
  sh[t] = v;
  __syncthreads();
  for (int off = 1; off < SCAN_B; off <<= 1) {
    int add = (t >= off) ? sh[t - off] : 0;
    __syncthreads();
    sh[t] += add;
    __syncthreads();
  }
  int excl = sh[t] - v + bsums[blockIdx.x];
  if (g < N_NODES) { row_ptr[g] = excl; cursor[g] = excl; }
}

// CSR build step 3: place src ids into dst buckets
__global__ __launch_bounds__(256) void place_kernel(
    const int* __restrict__ src, const int* __restrict__ dst,
    int* __restrict__ cursor, int* __restrict__ csr_src) {
  int e = blockIdx.x * 256 + threadIdx.x;
  if (e < N_EDGES) {
    int pos = atomicAdd(&cursor[dst[e]], 1);
    csr_src[pos] = src[e];
  }
}

// ---------------------------------------------------------------------------
// GEMM: out_bf16[N x C] = X[N x 128] @ W[128 x C], fp32 math, bf16 output.
// Register tile RT rows x 8 cols per thread; W staged in two K=64 halves to
// keep LDS <= 66.5KB (2 blocks/CU for C=128, 3 for C=64).
template <int C, int RT>
__global__ __launch_bounds__(256) void gemm_k128_kernel(
    const float* __restrict__ X, const float* __restrict__ W,
    unsigned short* __restrict__ out, int nrows) {
  constexpr int CG  = C / 8;          // col-groups: 16 (C=128) / 8 (C=64)
  constexpr int NRQ = 256 / CG;       // thread-rows: 16 / 32
  constexpr int BR  = NRQ * RT;       // block rows = 64 for both configs
  static_assert(BR == 64, "tile mismatch");
  constexpr int XP  = 132;            // sX pitch (floats): conflict-free reads

  __shared__ float sX[BR * XP];
  __shared__ float sW[64 * C];        // one K-half

  const int row0 = blockIdx.x * BR;

  // Stage X tile (float4)
  for (int t = threadIdx.x; t < BR * 32; t += 256) {
    int rr = t >> 5;
    int co = (t & 31) * 4;
    int g = row0 + rr;
    float4 v = make_float4(0.f, 0.f, 0.f, 0.f);
    if (g < nrows) v = *(const float4*)&X[(long)g * 128 + co];
    *(float4*)&sX[rr * XP + co] = v;
  }

  const int rq = threadIdx.x / CG;
  const int cg = threadIdx.x % CG;

  float acc[RT][8];
#pragma unroll
  for (int i = 0; i < RT; ++i)
#pragma unroll
    for (int j = 0; j < 8; ++j) acc[i][j] = 0.f;

  for (int kh = 0; kh < 2; ++kh) {
    __syncthreads();  // sX ready (kh=0) / previous sW readers done (kh=1)
    // Stage this K-half of W (float4, coalesced)
    for (int t = threadIdx.x; t < 64 * (C / 4); t += 256) {
      int kk = t / (C / 4);
      int cc = (t % (C / 4)) * 4;
      *(float4*)&sW[kk * C + cc] = *(const float4*)&W[(long)(kh * 64 + kk) * C + cc];
    }
    __syncthreads();

    const float* sXr = &sX[rq * RT * XP + kh * 64];
    const float* sWc = &sW[cg * 8];
#pragma unroll 8
    for (int k = 0; k < 64; ++k) {
      float4 wlo = *(const float4*)&sWc[k * C];
      float4 whi = *(const float4*)&sWc[k * C + 4];
      float xr[RT];
#pragma unroll
      for (int i = 0; i < RT; ++i) xr[i] = sXr[i * XP + k];
#pragma unroll
      for (int i = 0; i < RT; ++i) {
        acc[i][0] = fmaf(xr[i], wlo.x, acc[i][0]);
        acc[i][1] = fmaf(xr[i], wlo.y, acc[i][1]);
        acc[i][2] = fmaf(xr[i], wlo.z, acc[i][2]);
        acc[i][3] = fmaf(xr[i], wlo.w, acc[i][3]);
        acc[i][4] = fmaf(xr[i], whi.x, acc[i][4]);
        acc[i][5] = fmaf(xr[i], whi.y, acc[i][5]);
        acc[i][6] = fmaf(xr[i], whi.z, acc[i][6]);
        acc[i][7] = fmaf(xr[i], whi.w, acc[i][7]);
      }
    }
  }

  // bf16 RNE pack + store (16B per row)
  const int orow = row0 + rq * RT;
#pragma unroll
  for (int i = 0; i < RT; ++i) {
    if (orow + i < nrows) {
      uint4 p;
      p.x = pack2bf(acc[i][0], acc[i][1]);
      p.y = pack2bf(acc[i][2], acc[i][3]);
      p.z = pack2bf(acc[i][4], acc[i][5]);
      p.w = pack2bf(acc[i][6], acc[i][7]);
      *(uint4*)&out[(long)(orow + i) * C + cg * 8] = p;
    }
  }
}

// ---------------------------------------------------------------------------
// Gather aggregation, one wave per node, fused self-loop + bias + ReLU.
// hw is bf16; unroll-4 pipelined index loads; dinv[n] folded out of the loop.
// C=128: each lane owns 2 channels (one packed uint per row).
__global__ __launch_bounds__(256) void agg128_kernel(
    const int* __restrict__ row_ptr, const int* __restrict__ csr_src,
    const float* __restrict__ dinv, const unsigned* __restrict__ hw,  // [N][64] uints
    const float* __restrict__ bias, float* __restrict__ out) {
  int n = (blockIdx.x * 256 + threadIdx.x) >> 6;
  int lane = threadIdx.x & 63;
  if (n >= N_NODES) return;
  const int start = row_ptr[n], end = row_ptr[n + 1];
  float ax = 0.f, ay = 0.f;
  const int nq = (end - start) >> 2;
  int j = start;
  if (nq > 0) {
    int s0 = csr_src[j], s1 = csr_src[j + 1], s2 = csr_src[j + 2], s3 = csr_src[j + 3];
    for (int q = 0; q < nq; ++q) {
      j += 4;
      int jn = (q + 1 < nq) ? j : start;  // safe clamp on last iter
      int t0 = csr_src[jn], t1 = csr_src[jn + 1], t2 = csr_src[jn + 2], t3 = csr_src[jn + 3];
      float w0 = dinv[s0], w1 = dinv[s1], w2 = dinv[s2], w3 = dinv[s3];
      unsigned u0 = hw[(long)s0 * 64 + lane];
      unsigned u1 = hw[(long)s1 * 64 + lane];
      unsigned u2 = hw[(long)s2 * 64 + lane];
      unsigned u3 = hw[(long)s3 * 64 + lane];
      ax = fmaf(bflo_to_f(u0), w0, ax); ay = fmaf(bfhi_to_f(u0), w0, ay);
      ax = fmaf(bflo_to_f(u1), w1, ax); ay = fmaf(bfhi_to_f(u1), w1, ay);
      ax = fmaf(bflo_to_f(u2), w2, ax); ay = fmaf(bfhi_to_f(u2), w2, ay);
      ax = fmaf(bflo_to_f(u3), w3, ax); ay = fmaf(bfhi_to_f(u3), w3, ay);
      s0 = t0; s1 = t1; s2 = t2; s3 = t3;
    }
  }
  for (; j < end; ++j) {
    int s = csr_src[j];
    float w = dinv[s];
    unsigned u = hw[(long)s * 64 + lane];
    ax = fmaf(bflo_to_f(u), w, ax);
    ay = fmaf(bfhi_to_f(u), w, ay);
  }
  float dn = dinv[n];
  float sn = dn * dn;
  unsigned uh = hw[(long)n * 64 + lane];
  int c0 = lane * 2;
  float2 bb = *(const float2*)&bias[c0];
  float ox = fmaxf(fmaf(bflo_to_f(uh), sn, ax * dn) + bb.x, 0.f);
  float oy = fmaxf(fmaf(bfhi_to_f(uh), sn, ay * dn) + bb.y, 0.f);
  *(float2*)&out[(long)n * 128 + c0] = make_float2(ox, oy);
}

// C=64: each lane owns 1 channel (ushort loads).
__global__ __launch_bounds__(256) void agg64_kernel(
    const int* __restrict__ row_ptr, const int* __restrict__ csr_src,
    const float* __restrict__ dinv, const unsigned short* __restrict__ hw,  // [N][64]
    const float* __restrict__ bias, float* __restrict__ out) {
  int n = (blockIdx.x * 256 + threadIdx.x) >> 6;
  int lane = threadIdx.x & 63;
  if (n >= N_NODES) return;
  const int start = row_ptr[n], end = row_ptr[n + 1];
  float a = 0.f;
  const int nq = (end - start) >> 2;
  int j = start;
  if (nq > 0) {
    int s0 = csr_src[j], s1 = csr_src[j + 1], s2 = csr_src[j + 2], s3 = csr_src[j + 3];
    for (int q = 0; q < nq; ++q) {
      j += 4;
      int jn = (q + 1 < nq) ? j : start;
      int t0 = csr_src[jn], t1 = csr_src[jn + 1], t2 = csr_src[jn + 2], t3 = csr_src[jn + 3];
      float w0 = dinv[s0], w1 = dinv[s1], w2 = dinv[s2], w3 = dinv[s3];
      unsigned v0 = hw[(long)s0 * 64 + lane];
      unsigned v1 = hw[(long)s1 * 64 + lane];
      unsigned v2 = hw[(long)s2 * 64 + lane];
      unsigned v3 = hw[(long)s3 * 64 + lane];
      a = fmaf(bflo_to_f(v0), w0, a);
      a = fmaf(bflo_to_f(v1), w1, a);
      a = fmaf(bflo_to_f(v2), w2, a);
      a = fmaf(bflo_to_f(v3), w3, a);
      s0 = t0; s1 = t1; s2 = t2; s3 = t3;
    }
  }
  for (; j < end; ++j) {
    int s = csr_src[j];
    a = fmaf(bflo_to_f((unsigned)hw[(long)s * 64 + lane]), dinv[s], a);
  }
  float dn = dinv[n];
  float sn = dn * dn;
  float h = bflo_to_f((unsigned)hw[(long)n * 64 + lane]);
  float o = fmaxf(fmaf(h, sn, a * dn) + bias[lane], 0.f);
  out[(long)n * 64 + lane] = o;
}

// ---------------------------------------------------------------------------
extern "C" void kernel_launch(void* const* d_in, const int* in_sizes, int n_in,
                              void* d_out, int out_size, void* d_ws, size_t ws_size,
                              hipStream_t stream) {
  const float* x  = (const float*)d_in[0];
  const int*   ei = (const int*)d_in[1];
  const float* W1 = (const float*)d_in[2];
  const float* b1 = (const float*)d_in[3];
  const float* W2 = (const float*)d_in[4];
  const float* b2 = (const float*)d_in[5];
  float* out = (float*)d_out;

  const int* src = ei;             // edge_index[0]
  const int* dst = ei + N_EDGES;   // edge_index[1]

  // Workspace layout
  char* ws = (char*)d_ws;
  int*   deg     = (int*)ws;                         ws += 50048 * 4;
  float* dinv    = (float*)ws;                       ws += 50048 * 4;
  int*   row_ptr = (int*)ws;                         ws += 50048 * 4;
  int*   cursor  = (int*)ws;                         ws += 50048 * 4;
  int*   bsums   = (int*)ws;                         ws += 64 * 4;
  int*   csr_src = (int*)ws;                         ws += (size_t)N_EDGES * 4;
  unsigned short* hw1 = (unsigned short*)ws;         ws += (size_t)N_NODES * 128 * 2;  // bf16
  float* h1      = (float*)ws;                       ws += (size_t)N_NODES * 128 * 4;  // fp32
  unsigned short* hw2 = (unsigned short*)ws;         ws += (size_t)N_NODES * 64 * 2;   // bf16

  // ---- CSR build ----
  hipMemsetAsync(deg, 0, N_NODES * sizeof(int), stream);
  hist_kernel<<<(N_EDGES + 255) / 256, 256, 0, stream>>>(dst, deg);
  dinv_kernel<<<(N_NODES + 255) / 256, 256, 0, stream>>>(deg, dinv);
  scan_partial_kernel<<<NB, SCAN_B, 0, stream>>>(deg, bsums);
  scan_bsums_kernel<<<1, 64, 0, stream>>>(bsums, row_ptr);
  scan_final_kernel<<<NB, SCAN_B, 0, stream>>>(deg, bsums, row_ptr, cursor);
  place_kernel<<<(N_EDGES + 255) / 256, 256, 0, stream>>>(src, dst, cursor, csr_src);

  // ---- Layer 1 ----
  gemm_k128_kernel<128, 4><<<(N_NODES + 63) / 64, 256, 0, stream>>>(
      x, W1, hw1, N_NODES);
  agg128_kernel<<<(N_NODES * 64 + 255) / 256, 256, 0, stream>>>(
      row_ptr, csr_src, dinv, (const unsigned*)hw1, b1, h1);

  // ---- Layer 2 ----
  gemm_k128_kernel<64, 2><<<(N_NODES + 63) / 64, 256, 0, stream>>>(
      h1, W2, hw2, N_NODES);
  agg64_kernel<<<(N_NODES * 64 + 255) / 256, 256, 0, stream>>>(
      row_ptr, csr_src, dinv, hw2, b2, out);
}

// Round 5
// 172.909 us; speedup vs baseline: 12.6540x; 1.4271x over previous
//
#include <hip/hip_runtime.h>

// Problem constants (from reference)
#define N_NODES 50000
#define N_EDGES 800000
#define IN_CH   128
#define HID_CH  128
#define OUT_CH  64

#define SCAN_B  1024
#define NB ((N_NODES + SCAN_B - 1) / SCAN_B)   // 49

typedef __attribute__((ext_vector_type(8))) short v8s;
typedef __attribute__((ext_vector_type(4))) float v4f;

// ---------------------------------------------------------------------------
// bf16 helpers (RNE)
__device__ __forceinline__ unsigned bf16rne(float f) {
  unsigned u = __float_as_uint(f);
  return (u + 0x7fffu + ((u >> 16) & 1u)) >> 16;
}
__device__ __forceinline__ unsigned pack2bf(float a, float b) {
  return bf16rne(a) | (bf16rne(b) << 16);
}
__device__ __forceinline__ float bfhi_to_f(unsigned u) {   // high ushort
  return __uint_as_float(u & 0xffff0000u);
}
__device__ __forceinline__ float bflo_to_f(unsigned u) {   // low ushort
  return __uint_as_float(u << 16);
}

// ---------------------------------------------------------------------------
// CSR build step 1: degree histogram over dst; atomic return value IS the rank
__global__ __launch_bounds__(256) void hist_kernel(
    const int* __restrict__ dst, int* __restrict__ deg, int* __restrict__ rank) {
  int e = blockIdx.x * 256 + threadIdx.x;
  if (e < N_EDGES) rank[e] = atomicAdd(&deg[dst[e]], 1);
}

// dinv[n] = rsqrt(deg[n] + 1)  (self-loop included)
__global__ __launch_bounds__(256) void dinv_kernel(
    const int* __restrict__ deg, float* __restrict__ dinv) {
  int n = blockIdx.x * 256 + threadIdx.x;
  if (n < N_NODES) dinv[n] = rsqrtf((float)deg[n] + 1.0f);
}

// CSR build step 2a: per-chunk sums
__global__ __launch_bounds__(SCAN_B) void scan_partial_kernel(
    const int* __restrict__ deg, int* __restrict__ bsums) {
  __shared__ int sh[SCAN_B];
  int t = threadIdx.x;
  int g = blockIdx.x * SCAN_B + t;
  sh[t] = (g < N_NODES) ? deg[g] : 0;
  __syncthreads();
  for (int off = SCAN_B / 2; off > 0; off >>= 1) {
    if (t < off) sh[t] += sh[t + off];
    __syncthreads();
  }
  if (t == 0) bsums[blockIdx.x] = sh[0];
}

// CSR build step 2b: exclusive scan of the (tiny) chunk sums
__global__ __launch_bounds__(64) void scan_bsums_kernel(
    int* __restrict__ bsums, int* __restrict__ row_ptr) {
  __shared__ int sh[NB];
  int t = threadIdx.x;
  if (t < NB) sh[t] = bsums[t];
  __syncthreads();
  if (t == 0) {
    int acc = 0;
    for (int b = 0; b < NB; ++b) { int v = sh[b]; sh[b] = acc; acc += v; }
    row_ptr[N_NODES] = acc;  // == N_EDGES
  }
  __syncthreads();
  if (t < NB) bsums[t] = sh[t];
}

// CSR build step 2c: per-chunk exclusive scan + offset -> row_ptr
__global__ __launch_bounds__(SCAN_B) void scan_final_kernel(
    const int* __restrict__ deg, const int* __restrict__ bsums,
    int* __restrict__ row_ptr) {
  __shared__ int sh[SCAN_B];
  int t = threadIdx.x;
  int g = blockIdx.x * SCAN_B + t;
  int v = (g < N_NODES) ? deg[g] : 0;
  sh[t] = v;
  __syncthreads();
  for (int off = 1; off < SCAN_B; off <<= 1) {
    int add = (t >= off) ? sh[t - off] : 0;
    __syncthreads();
    sh[t] += add;
    __syncthreads();
  }
  int excl = sh[t] - v + bsums[blockIdx.x];
  if (g < N_NODES) row_ptr[g] = excl;
}

// CSR build step 3: place src ids (atomic-free; rank precomputed in hist)
__global__ __launch_bounds__(256) void place_kernel(
    const int* __restrict__ src, const int* __restrict__ dst,
    const int* __restrict__ rank, const int* __restrict__ row_ptr,
    int* __restrict__ csr_src) {
  int e = blockIdx.x * 256 + threadIdx.x;
  if (e < N_EDGES) {
    csr_src[row_ptr[dst[e]] + rank[e]] = src[e];
  }
}

// ---------------------------------------------------------------------------
// fp32 -> bf16 convert (8 elems/thread)
__global__ __launch_bounds__(256) void cvt_bf16_kernel(
    const float* __restrict__ in, unsigned short* __restrict__ out, int n8) {
  int i = blockIdx.x * 256 + threadIdx.x;
  if (i >= n8) return;
  float4 f0 = *(const float4*)&in[(long)i * 8];
  float4 f1 = *(const float4*)&in[(long)i * 8 + 4];
  uint4 p;
  p.x = pack2bf(f0.x, f0.y); p.y = pack2bf(f0.z, f0.w);
  p.z = pack2bf(f1.x, f1.y); p.w = pack2bf(f1.z, f1.w);
  *(uint4*)&out[(long)i * 8] = p;
}

// W [128][C] fp32 -> Wt [C][128] bf16 (transpose + convert)
template <int C>
__global__ __launch_bounds__(256) void cvt_wt_kernel(
    const float* __restrict__ W, unsigned short* __restrict__ Wt) {
  int idx = blockIdx.x * 256 + threadIdx.x;
  if (idx < 128 * C) {
    int k = idx / C, c = idx % C;
    Wt[c * 128 + k] = (unsigned short)bf16rne(W[idx]);
  }
}

// ---------------------------------------------------------------------------
// MFMA GEMM: out[nrows x N] bf16 = A[nrows x 128] bf16 @ Bt^T, Bt = [N][128] bf16.
// Block = 256 (4 waves), 64 rows/block (16/wave). mfma_f32_16x16x32_bf16.
// A frag: row = lane&15, k-octet = lane>>4. C/D: col = lane&15, row = (lane>>4)*4+i.
template <int N>
__global__ __launch_bounds__(256) void gemm_mfma_kernel(
    const unsigned short* __restrict__ A, const unsigned short* __restrict__ Bt,
    unsigned short* __restrict__ out, int nrows) {
  constexpr int KP = 136;   // padded pitch (bf16): 272B rows, 16B-aligned, ~2-way banks
  __shared__ unsigned short sA[64 * KP];
  __shared__ unsigned short sB[N * KP];

  const int row0 = blockIdx.x * 64;
  const int t = threadIdx.x;

  // Stage A tile: 64 rows x 16 chunks of 16B (coalesced)
  for (int i = t; i < 64 * 16; i += 256) {
    int r = i >> 4, ch = i & 15;
    uint4 v = make_uint4(0u, 0u, 0u, 0u);
    if (row0 + r < nrows) v = *(const uint4*)&A[(long)(row0 + r) * 128 + ch * 8];
    *(uint4*)&sA[r * KP + ch * 8] = v;
  }
  // Stage Bt: N rows x 16 chunks
  for (int i = t; i < N * 16; i += 256) {
    int r = i >> 4, ch = i & 15;
    *(uint4*)&sB[r * KP + ch * 8] = *(const uint4*)&Bt[(long)r * 128 + ch * 8];
  }
  __syncthreads();

  const int wave = t >> 6, lane = t & 63;
  const int m0 = wave * 16;
  const int lr = lane & 15;
  const int kg = lane >> 4;

  constexpr int NT = N / 16;
  v4f acc[NT];
#pragma unroll
  for (int i = 0; i < NT; ++i) acc[i] = (v4f)(0.f);

#pragma unroll
  for (int ks = 0; ks < 4; ++ks) {
    const int k0 = ks * 32 + kg * 8;
    v8s a = *(const v8s*)&sA[(m0 + lr) * KP + k0];
#pragma unroll
    for (int nt = 0; nt < NT; ++nt) {
      v8s b = *(const v8s*)&sB[(nt * 16 + lr) * KP + k0];
      acc[nt] = __builtin_amdgcn_mfma_f32_16x16x32_bf16(a, b, acc[nt], 0, 0, 0);
    }
  }

#pragma unroll
  for (int nt = 0; nt < NT; ++nt) {
#pragma unroll
    for (int i = 0; i < 4; ++i) {
      int gr = row0 + m0 + kg * 4 + i;
      if (gr < nrows)
        out[(long)gr * N + nt * 16 + lr] = (unsigned short)bf16rne(acc[nt][i]);
    }
  }
}

// ---------------------------------------------------------------------------
// Gather aggregation, one wave per node, fused self-loop + bias + ReLU.
// hw bf16 packed; h1 output bf16 packed (feeds MFMA GEMM2).
__global__ __launch_bounds__(256) void agg128_kernel(
    const int* __restrict__ row_ptr, const int* __restrict__ csr_src,
    const float* __restrict__ dinv, const unsigned* __restrict__ hw,  // [N][64] u32
    const float* __restrict__ bias, unsigned* __restrict__ h1out) {   // [N][64] u32
  int n = (blockIdx.x * 256 + threadIdx.x) >> 6;
  int lane = threadIdx.x & 63;
  if (n >= N_NODES) return;
  const int start = row_ptr[n], end = row_ptr[n + 1];
  float ax = 0.f, ay = 0.f;
  const int nq = (end - start) >> 2;
  int j = start;
  if (nq > 0) {
    int s0 = csr_src[j], s1 = csr_src[j + 1], s2 = csr_src[j + 2], s3 = csr_src[j + 3];
    for (int q = 0; q < nq; ++q) {
      j += 4;
      int jn = (q + 1 < nq) ? j : start;  // safe clamp on last iter
      int t0 = csr_src[jn], t1 = csr_src[jn + 1], t2 = csr_src[jn + 2], t3 = csr_src[jn + 3];
      float w0 = dinv[s0], w1 = dinv[s1], w2 = dinv[s2], w3 = dinv[s3];
      unsigned u0 = hw[(long)s0 * 64 + lane];
      unsigned u1 = hw[(long)s1 * 64 + lane];
      unsigned u2 = hw[(long)s2 * 64 + lane];
      unsigned u3 = hw[(long)s3 * 64 + lane];
      ax = fmaf(bflo_to_f(u0), w0, ax); ay = fmaf(bfhi_to_f(u0), w0, ay);
      ax = fmaf(bflo_to_f(u1), w1, ax); ay = fmaf(bfhi_to_f(u1), w1, ay);
      ax = fmaf(bflo_to_f(u2), w2, ax); ay = fmaf(bfhi_to_f(u2), w2, ay);
      ax = fmaf(bflo_to_f(u3), w3, ax); ay = fmaf(bfhi_to_f(u3), w3, ay);
      s0 = t0; s1 = t1; s2 = t2; s3 = t3;
    }
  }
  for (; j < end; ++j) {
    int s = csr_src[j];
    float w = dinv[s];
    unsigned u = hw[(long)s * 64 + lane];
    ax = fmaf(bflo_to_f(u), w, ax);
    ay = fmaf(bfhi_to_f(u), w, ay);
  }
  float dn = dinv[n];
  float sn = dn * dn;
  unsigned uh = hw[(long)n * 64 + lane];
  int c0 = lane * 2;
  float2 bb = *(const float2*)&bias[c0];
  float ox = fmaxf(fmaf(bflo_to_f(uh), sn, ax * dn) + bb.x, 0.f);
  float oy = fmaxf(fmaf(bfhi_to_f(uh), sn, ay * dn) + bb.y, 0.f);
  h1out[(long)n * 64 + lane] = pack2bf(ox, oy);
}

// C=64: each lane owns 1 channel; fp32 output (final).
__global__ __launch_bounds__(256) void agg64_kernel(
    const int* __restrict__ row_ptr, const int* __restrict__ csr_src,
    const float* __restrict__ dinv, const unsigned short* __restrict__ hw,  // [N][64]
    const float* __restrict__ bias, float* __restrict__ out) {
  int n = (blockIdx.x * 256 + threadIdx.x) >> 6;
  int lane = threadIdx.x & 63;
  if (n >= N_NODES) return;
  const int start = row_ptr[n], end = row_ptr[n + 1];
  float a = 0.f;
  const int nq = (end - start) >> 2;
  int j = start;
  if (nq > 0) {
    int s0 = csr_src[j], s1 = csr_src[j + 1], s2 = csr_src[j + 2], s3 = csr_src[j + 3];
    for (int q = 0; q < nq; ++q) {
      j += 4;
      int jn = (q + 1 < nq) ? j : start;
      int t0 = csr_src[jn], t1 = csr_src[jn + 1], t2 = csr_src[jn + 2], t3 = csr_src[jn + 3];
      float w0 = dinv[s0], w1 = dinv[s1], w2 = dinv[s2], w3 = dinv[s3];
      unsigned v0 = hw[(long)s0 * 64 + lane];
      unsigned v1 = hw[(long)s1 * 64 + lane];
      unsigned v2 = hw[(long)s2 * 64 + lane];
      unsigned v3 = hw[(long)s3 * 64 + lane];
      a = fmaf(bflo_to_f(v0), w0, a);
      a = fmaf(bflo_to_f(v1), w1, a);
      a = fmaf(bflo_to_f(v2), w2, a);
      a = fmaf(bflo_to_f(v3), w3, a);
      s0 = t0; s1 = t1; s2 = t2; s3 = t3;
    }
  }
  for (; j < end; ++j) {
    int s = csr_src[j];
    a = fmaf(bflo_to_f((unsigned)hw[(long)s * 64 + lane]), dinv[s], a);
  }
  float dn = dinv[n];
  float sn = dn * dn;
  float h = bflo_to_f((unsigned)hw[(long)n * 64 + lane]);
  float o = fmaxf(fmaf(h, sn, a * dn) + bias[lane], 0.f);
  out[(long)n * 64 + lane] = o;
}

// ---------------------------------------------------------------------------
extern "C" void kernel_launch(void* const* d_in, const int* in_sizes, int n_in,
                              void* d_out, int out_size, void* d_ws, size_t ws_size,
                              hipStream_t stream) {
  const float* x  = (const float*)d_in[0];
  const int*   ei = (const int*)d_in[1];
  const float* W1 = (const float*)d_in[2];
  const float* b1 = (const float*)d_in[3];
  const float* W2 = (const float*)d_in[4];
  const float* b2 = (const float*)d_in[5];
  float* out = (float*)d_out;

  const int* src = ei;             // edge_index[0]
  const int* dst = ei + N_EDGES;   // edge_index[1]

  // Workspace layout (bytes; every chunk is a multiple of 256B)
  char* ws = (char*)d_ws;
  int*   deg     = (int*)ws;                     ws += 50048 * 4;
  float* dinv    = (float*)ws;                   ws += 50048 * 4;
  int*   row_ptr = (int*)ws;                     ws += 50048 * 4;
  int*   bsums   = (int*)ws;                     ws += 64 * 4;
  int*   rank    = (int*)ws;                     ws += (size_t)N_EDGES * 4;
  int*   csr_src = (int*)ws;                     ws += (size_t)N_EDGES * 4;
  unsigned short* Xb  = (unsigned short*)ws;     ws += (size_t)N_NODES * 128 * 2;
  unsigned short* Wt1 = (unsigned short*)ws;     ws += 128 * 128 * 2;
  unsigned short* Wt2 = (unsigned short*)ws;     ws += 64 * 128 * 2;
  unsigned short* hw1 = (unsigned short*)ws;     ws += (size_t)N_NODES * 128 * 2;
  unsigned*       h1  = (unsigned*)ws;           ws += (size_t)N_NODES * 64 * 4;
  unsigned short* hw2 = (unsigned short*)ws;     ws += (size_t)N_NODES * 64 * 2;

  // ---- CSR build ----
  hipMemsetAsync(deg, 0, N_NODES * sizeof(int), stream);
  hist_kernel<<<(N_EDGES + 255) / 256, 256, 0, stream>>>(dst, deg, rank);
  dinv_kernel<<<(N_NODES + 255) / 256, 256, 0, stream>>>(deg, dinv);
  scan_partial_kernel<<<NB, SCAN_B, 0, stream>>>(deg, bsums);
  scan_bsums_kernel<<<1, 64, 0, stream>>>(bsums, row_ptr);
  scan_final_kernel<<<NB, SCAN_B, 0, stream>>>(deg, bsums, row_ptr);
  place_kernel<<<(N_EDGES + 255) / 256, 256, 0, stream>>>(src, dst, rank, row_ptr, csr_src);

  // ---- Precision conversions ----
  cvt_bf16_kernel<<<(N_NODES * 128 / 8 + 255) / 256, 256, 0, stream>>>(
      x, Xb, N_NODES * 128 / 8);
  cvt_wt_kernel<128><<<64, 256, 0, stream>>>(W1, Wt1);
  cvt_wt_kernel<64><<<32, 256, 0, stream>>>(W2, Wt2);

  // ---- Layer 1 ----
  gemm_mfma_kernel<128><<<(N_NODES + 63) / 64, 256, 0, stream>>>(
      Xb, Wt1, hw1, N_NODES);
  agg128_kernel<<<(N_NODES * 64 + 255) / 256, 256, 0, stream>>>(
      row_ptr, csr_src, dinv, (const unsigned*)hw1, b1, h1);

  // ---- Layer 2 ----
  gemm_mfma_kernel<64><<<(N_NODES + 63) / 64, 256, 0, stream>>>(
      (const unsigned short*)h1, Wt2, hw2, N_NODES);
  agg64_kernel<<<(N_NODES * 64 + 255) / 256, 256, 0, stream>>>(
      row_ptr, csr_src, dinv, hw2, b2, out);
}

// Round 6
// 167.515 us; speedup vs baseline: 13.0614x; 1.0322x over previous
//
#include <hip/hip_runtime.h>

// Problem constants (from reference)
#define N_NODES 50000
#define N_EDGES 800000
#define IN_CH   128
#define HID_CH  128
#define OUT_CH  64

#define SCAN_B  1024
#define NB ((N_NODES + SCAN_B - 1) / SCAN_B)   // 49

typedef __attribute__((ext_vector_type(8))) short v8s;
typedef __attribute__((ext_vector_type(4))) float v4f;

// ---------------------------------------------------------------------------
// bf16 helpers (RNE)
__device__ __forceinline__ unsigned bf16rne(float f) {
  unsigned u = __float_as_uint(f);
  return (u + 0x7fffu + ((u >> 16) & 1u)) >> 16;
}
__device__ __forceinline__ unsigned pack2bf(float a, float b) {
  return bf16rne(a) | (bf16rne(b) << 16);
}
__device__ __forceinline__ float bfhi_to_f(unsigned u) {   // high ushort
  return __uint_as_float(u & 0xffff0000u);
}
__device__ __forceinline__ float bflo_to_f(unsigned u) {   // low ushort
  return __uint_as_float(u << 16);
}

// ---------------------------------------------------------------------------
// Zero deg[] (replaces hipMemsetAsync's 43us fill node): 12512 uint4 = 200KB
__global__ __launch_bounds__(256) void zero_deg_kernel(int* __restrict__ deg) {
  int i = blockIdx.x * 256 + threadIdx.x;
  if (i < 50048 / 4) *(uint4*)&deg[i * 4] = make_uint4(0u, 0u, 0u, 0u);
}

// CSR build step 1: degree histogram over dst; atomic return value IS the rank
__global__ __launch_bounds__(256) void hist_kernel(
    const int* __restrict__ dst, int* __restrict__ deg, int* __restrict__ rank) {
  int e = blockIdx.x * 256 + threadIdx.x;
  if (e < N_EDGES) rank[e] = atomicAdd(&deg[dst[e]], 1);
}

// dinv[n] = rsqrt(deg[n] + 1)  (self-loop included)
__global__ __launch_bounds__(256) void dinv_kernel(
    const int* __restrict__ deg, float* __restrict__ dinv) {
  int n = blockIdx.x * 256 + threadIdx.x;
  if (n < N_NODES) dinv[n] = rsqrtf((float)deg[n] + 1.0f);
}

// CSR build step 2a: per-chunk sums
__global__ __launch_bounds__(SCAN_B) void scan_partial_kernel(
    const int* __restrict__ deg, int* __restrict__ bsums) {
  __shared__ int sh[SCAN_B];
  int t = threadIdx.x;
  int g = blockIdx.x * SCAN_B + t;
  sh[t] = (g < N_NODES) ? deg[g] : 0;
  __syncthreads();
  for (int off = SCAN_B / 2; off > 0; off >>= 1) {
    if (t < off) sh[t] += sh[t + off];
    __syncthreads();
  }
  if (t == 0) bsums[blockIdx.x] = sh[0];
}

// CSR build step 2b: exclusive scan of the (tiny) chunk sums
__global__ __launch_bounds__(64) void scan_bsums_kernel(
    int* __restrict__ bsums, int* __restrict__ row_ptr) {
  __shared__ int sh[NB];
  int t = threadIdx.x;
  if (t < NB) sh[t] = bsums[t];
  __syncthreads();
  if (t == 0) {
    int acc = 0;
    for (int b = 0; b < NB; ++b) { int v = sh[b]; sh[b] = acc; acc += v; }
    row_ptr[N_NODES] = acc;  // == N_EDGES
  }
  __syncthreads();
  if (t < NB) bsums[t] = sh[t];
}

// CSR build step 2c: per-chunk exclusive scan + offset -> row_ptr
__global__ __launch_bounds__(SCAN_B) void scan_final_kernel(
    const int* __restrict__ deg, const int* __restrict__ bsums,
    int* __restrict__ row_ptr) {
  __shared__ int sh[SCAN_B];
  int t = threadIdx.x;
  int g = blockIdx.x * SCAN_B + t;
  int v = (g < N_NODES) ? deg[g] : 0;
  sh[t] = v;
  __syncthreads();
  for (int off = 1; off < SCAN_B; off <<= 1) {
    int add = (t >= off) ? sh[t - off] : 0;
    __syncthreads();
    sh[t] += add;
    __syncthreads();
  }
  int excl = sh[t] - v + bsums[blockIdx.x];
  if (g < N_NODES) row_ptr[g] = excl;
}

// CSR build step 3: place src ids (atomic-free; rank precomputed in hist)
__global__ __launch_bounds__(256) void place_kernel(
    const int* __restrict__ src, const int* __restrict__ dst,
    const int* __restrict__ rank, const int* __restrict__ row_ptr,
    int* __restrict__ csr_src) {
  int e = blockIdx.x * 256 + threadIdx.x;
  if (e < N_EDGES) {
    csr_src[row_ptr[dst[e]] + rank[e]] = src[e];
  }
}

// ---------------------------------------------------------------------------
// W [128][C] fp32 -> Wt [C][128] bf16 (transpose + convert)
template <int C>
__global__ __launch_bounds__(256) void cvt_wt_kernel(
    const float* __restrict__ W, unsigned short* __restrict__ Wt) {
  int idx = blockIdx.x * 256 + threadIdx.x;
  if (idx < 128 * C) {
    int k = idx / C, c = idx % C;
    Wt[c * 128 + k] = (unsigned short)bf16rne(W[idx]);
  }
}

// ---------------------------------------------------------------------------
// MFMA GEMM: out[nrows x N] bf16 = A[nrows x 128] @ Bt^T, Bt = [N][128] bf16.
// A is fp32 (AFP32=true, converted during LDS staging) or bf16.
// Block = 256 (4 waves), 64 rows/block (16/wave). mfma_f32_16x16x32_bf16.
// A frag: row = lane&15, k-octet = lane>>4. C/D: col = lane&15, row = (lane>>4)*4+i.
template <int N, bool AFP32>
__global__ __launch_bounds__(256) void gemm_mfma_kernel(
    const void* __restrict__ Av, const unsigned short* __restrict__ Bt,
    unsigned short* __restrict__ out, int nrows) {
  constexpr int KP = 136;   // padded pitch (bf16): 272B rows, 16B-aligned, ~2-way banks
  __shared__ unsigned short sA[64 * KP];
  __shared__ unsigned short sB[N * KP];

  const int row0 = blockIdx.x * 64;
  const int t = threadIdx.x;

  // Stage A tile: 64 rows x 16 chunks of 8 bf16 elems (coalesced)
  for (int i = t; i < 64 * 16; i += 256) {
    int r = i >> 4, ch = i & 15;
    uint4 v = make_uint4(0u, 0u, 0u, 0u);
    if (row0 + r < nrows) {
      if constexpr (AFP32) {
        const float* A = (const float*)Av;
        float4 f0 = *(const float4*)&A[(long)(row0 + r) * 128 + ch * 8];
        float4 f1 = *(const float4*)&A[(long)(row0 + r) * 128 + ch * 8 + 4];
        v.x = pack2bf(f0.x, f0.y); v.y = pack2bf(f0.z, f0.w);
        v.z = pack2bf(f1.x, f1.y); v.w = pack2bf(f1.z, f1.w);
      } else {
        const unsigned short* A = (const unsigned short*)Av;
        v = *(const uint4*)&A[(long)(row0 + r) * 128 + ch * 8];
      }
    }
    *(uint4*)&sA[r * KP + ch * 8] = v;
  }
  // Stage Bt: N rows x 16 chunks
  for (int i = t; i < N * 16; i += 256) {
    int r = i >> 4, ch = i & 15;
    *(uint4*)&sB[r * KP + ch * 8] = *(const uint4*)&Bt[(long)r * 128 + ch * 8];
  }
  __syncthreads();

  const int wave = t >> 6, lane = t & 63;
  const int m0 = wave * 16;
  const int lr = lane & 15;
  const int kg = lane >> 4;

  constexpr int NT = N / 16;
  v4f acc[NT];
#pragma unroll
  for (int i = 0; i < NT; ++i) acc[i] = (v4f)(0.f);

#pragma unroll
  for (int ks = 0; ks < 4; ++ks) {
    const int k0 = ks * 32 + kg * 8;
    v8s a = *(const v8s*)&sA[(m0 + lr) * KP + k0];
#pragma unroll
    for (int nt = 0; nt < NT; ++nt) {
      v8s b = *(const v8s*)&sB[(nt * 16 + lr) * KP + k0];
      acc[nt] = __builtin_amdgcn_mfma_f32_16x16x32_bf16(a, b, acc[nt], 0, 0, 0);
    }
  }

#pragma unroll
  for (int nt = 0; nt < NT; ++nt) {
#pragma unroll
    for (int i = 0; i < 4; ++i) {
      int gr = row0 + m0 + kg * 4 + i;
      if (gr < nrows)
        out[(long)gr * N + nt * 16 + lr] = (unsigned short)bf16rne(acc[nt][i]);
    }
  }
}

// ---------------------------------------------------------------------------
// Gather aggregation, one wave per node, fused self-loop + bias + ReLU.
// hw bf16 packed; h1 output bf16 packed (feeds MFMA GEMM2).
__global__ __launch_bounds__(256) void agg128_kernel(
    const int* __restrict__ row_ptr, const int* __restrict__ csr_src,
    const float* __restrict__ dinv, const unsigned* __restrict__ hw,  // [N][64] u32
    const float* __restrict__ bias, unsigned* __restrict__ h1out) {   // [N][64] u32
  int n = (blockIdx.x * 256 + threadIdx.x) >> 6;
  int lane = threadIdx.x & 63;
  if (n >= N_NODES) return;
  const int start = row_ptr[n], end = row_ptr[n + 1];
  float ax = 0.f, ay = 0.f;
  const int nq = (end - start) >> 2;
  int j = start;
  if (nq > 0) {
    int s0 = csr_src[j], s1 = csr_src[j + 1], s2 = csr_src[j + 2], s3 = csr_src[j + 3];
    for (int q = 0; q < nq; ++q) {
      j += 4;
      int jn = (q + 1 < nq) ? j : start;  // safe clamp on last iter
      int t0 = csr_src[jn], t1 = csr_src[jn + 1], t2 = csr_src[jn + 2], t3 = csr_src[jn + 3];
      float w0 = dinv[s0], w1 = dinv[s1], w2 = dinv[s2], w3 = dinv[s3];
      unsigned u0 = hw[(long)s0 * 64 + lane];
      unsigned u1 = hw[(long)s1 * 64 + lane];
      unsigned u2 = hw[(long)s2 * 64 + lane];
      unsigned u3 = hw[(long)s3 * 64 + lane];
      ax = fmaf(bflo_to_f(u0), w0, ax); ay = fmaf(bfhi_to_f(u0), w0, ay);
      ax = fmaf(bflo_to_f(u1), w1, ax); ay = fmaf(bfhi_to_f(u1), w1, ay);
      ax = fmaf(bflo_to_f(u2), w2, ax); ay = fmaf(bfhi_to_f(u2), w2, ay);
      ax = fmaf(bflo_to_f(u3), w3, ax); ay = fmaf(bfhi_to_f(u3), w3, ay);
      s0 = t0; s1 = t1; s2 = t2; s3 = t3;
    }
  }
  for (; j < end; ++j) {
    int s = csr_src[j];
    float w = dinv[s];
    unsigned u = hw[(long)s * 64 + lane];
    ax = fmaf(bflo_to_f(u), w, ax);
    ay = fmaf(bfhi_to_f(u), w, ay);
  }
  float dn = dinv[n];
  float sn = dn * dn;
  unsigned uh = hw[(long)n * 64 + lane];
  int c0 = lane * 2;
  float2 bb = *(const float2*)&bias[c0];
  float ox = fmaxf(fmaf(bflo_to_f(uh), sn, ax * dn) + bb.x, 0.f);
  float oy = fmaxf(fmaf(bfhi_to_f(uh), sn, ay * dn) + bb.y, 0.f);
  h1out[(long)n * 64 + lane] = pack2bf(ox, oy);
}

// C=64: each lane owns 1 channel; fp32 output (final).
__global__ __launch_bounds__(256) void agg64_kernel(
    const int* __restrict__ row_ptr, const int* __restrict__ csr_src,
    const float* __restrict__ dinv, const unsigned short* __restrict__ hw,  // [N][64]
    const float* __restrict__ bias, float* __restrict__ out) {
  int n = (blockIdx.x * 256 + threadIdx.x) >> 6;
  int lane = threadIdx.x & 63;
  if (n >= N_NODES) return;
  const int start = row_ptr[n], end = row_ptr[n + 1];
  float a = 0.f;
  const int nq = (end - start) >> 2;
  int j = start;
  if (nq > 0) {
    int s0 = csr_src[j], s1 = csr_src[j + 1], s2 = csr_src[j + 2], s3 = csr_src[j + 3];
    for (int q = 0; q < nq; ++q) {
      j += 4;
      int jn = (q + 1 < nq) ? j : start;
      int t0 = csr_src[jn], t1 = csr_src[jn + 1], t2 = csr_src[jn + 2], t3 = csr_src[jn + 3];
      float w0 = dinv[s0], w1 = dinv[s1], w2 = dinv[s2], w3 = dinv[s3];
      unsigned v0 = hw[(long)s0 * 64 + lane];
      unsigned v1 = hw[(long)s1 * 64 + lane];
      unsigned v2 = hw[(long)s2 * 64 + lane];
      unsigned v3 = hw[(long)s3 * 64 + lane];
      a = fmaf(bflo_to_f(v0), w0, a);
      a = fmaf(bflo_to_f(v1), w1, a);
      a = fmaf(bflo_to_f(v2), w2, a);
      a = fmaf(bflo_to_f(v3), w3, a);
      s0 = t0; s1 = t1; s2 = t2; s3 = t3;
    }
  }
  for (; j < end; ++j) {
    int s = csr_src[j];
    a = fmaf(bflo_to_f((unsigned)hw[(long)s * 64 + lane]), dinv[s], a);
  }
  float dn = dinv[n];
  float sn = dn * dn;
  float h = bflo_to_f((unsigned)hw[(long)n * 64 + lane]);
  float o = fmaxf(fmaf(h, sn, a * dn) + bias[lane], 0.f);
  out[(long)n * 64 + lane] = o;
}

// ---------------------------------------------------------------------------
extern "C" void kernel_launch(void* const* d_in, const int* in_sizes, int n_in,
                              void* d_out, int out_size, void* d_ws, size_t ws_size,
                              hipStream_t stream) {
  const float* x  = (const float*)d_in[0];
  const int*   ei = (const int*)d_in[1];
  const float* W1 = (const float*)d_in[2];
  const float* b1 = (const float*)d_in[3];
  const float* W2 = (const float*)d_in[4];
  const float* b2 = (const float*)d_in[5];
  float* out = (float*)d_out;

  const int* src = ei;             // edge_index[0]
  const int* dst = ei + N_EDGES;   // edge_index[1]

  // Workspace layout (bytes; every chunk is a multiple of 256B)
  char* ws = (char*)d_ws;
  int*   deg     = (int*)ws;                     ws += 50048 * 4;
  float* dinv    = (float*)ws;                   ws += 50048 * 4;
  int*   row_ptr = (int*)ws;                     ws += 50048 * 4;
  int*   bsums   = (int*)ws;                     ws += 64 * 4;
  int*   rank    = (int*)ws;                     ws += (size_t)N_EDGES * 4;
  int*   csr_src = (int*)ws;                     ws += (size_t)N_EDGES * 4;
  unsigned short* Wt1 = (unsigned short*)ws;     ws += 128 * 128 * 2;
  unsigned short* Wt2 = (unsigned short*)ws;     ws += 64 * 128 * 2;
  unsigned short* hw1 = (unsigned short*)ws;     ws += (size_t)N_NODES * 128 * 2;
  unsigned*       h1  = (unsigned*)ws;           ws += (size_t)N_NODES * 64 * 4;
  unsigned short* hw2 = (unsigned short*)ws;     ws += (size_t)N_NODES * 64 * 2;

  // ---- CSR build ----
  zero_deg_kernel<<<49, 256, 0, stream>>>(deg);
  hist_kernel<<<(N_EDGES + 255) / 256, 256, 0, stream>>>(dst, deg, rank);
  dinv_kernel<<<(N_NODES + 255) / 256, 256, 0, stream>>>(deg, dinv);
  scan_partial_kernel<<<NB, SCAN_B, 0, stream>>>(deg, bsums);
  scan_bsums_kernel<<<1, 64, 0, stream>>>(bsums, row_ptr);
  scan_final_kernel<<<NB, SCAN_B, 0, stream>>>(deg, bsums, row_ptr);
  place_kernel<<<(N_EDGES + 255) / 256, 256, 0, stream>>>(src, dst, rank, row_ptr, csr_src);

  // ---- Weight conversions (tiny) ----
  cvt_wt_kernel<128><<<64, 256, 0, stream>>>(W1, Wt1);
  cvt_wt_kernel<64><<<32, 256, 0, stream>>>(W2, Wt2);

  // ---- Layer 1 (x converted to bf16 inside GEMM staging) ----
  gemm_mfma_kernel<128, true><<<(N_NODES + 63) / 64, 256, 0, stream>>>(
      x, Wt1, hw1, N_NODES);
  agg128_kernel<<<(N_NODES * 64 + 255) / 256, 256, 0, stream>>>(
      row_ptr, csr_src, dinv, (const unsigned*)hw1, b1, h1);

  // ---- Layer 2 ----
  gemm_mfma_kernel<64, false><<<(N_NODES + 63) / 64, 256, 0, stream>>>(
      h1, Wt2, hw2, N_NODES);
  agg64_kernel<<<(N_NODES * 64 + 255) / 256, 256, 0, stream>>>(
      row_ptr, csr_src, dinv, hw2, b2, out);
}

// Round 7
// 142.757 us; speedup vs baseline: 15.3267x; 1.1734x over previous
//
#include <hip/hip_runtime.h>

// Problem constants (from reference)
#define N_NODES 50000
#define N_EDGES 800000
#define IN_CH   128
#define HID_CH  128
#define OUT_CH  64

#define SCAN_B  1024
#define NB ((N_NODES + SCAN_B - 1) / SCAN_B)   // 49

typedef __attribute__((ext_vector_type(8))) short v8s;
typedef __attribute__((ext_vector_type(4))) float v4f;

// ---------------------------------------------------------------------------
// bf16 helpers (RNE)
__device__ __forceinline__ unsigned bf16rne(float f) {
  unsigned u = __float_as_uint(f);
  return (u + 0x7fffu + ((u >> 16) & 1u)) >> 16;
}
__device__ __forceinline__ unsigned pack2bf(float a, float b) {
  return bf16rne(a) | (bf16rne(b) << 16);
}
__device__ __forceinline__ float bfhi_to_f(unsigned u) {   // high ushort
  return __uint_as_float(u & 0xffff0000u);
}
__device__ __forceinline__ float bflo_to_f(unsigned u) {   // low ushort
  return __uint_as_float(u << 16);
}

// ---------------------------------------------------------------------------
// Zero deg[]: 200KB of uint4 stores
__global__ __launch_bounds__(256) void zero_deg_kernel(int* __restrict__ deg) {
  int i = blockIdx.x * 256 + threadIdx.x;
  if (i < 50048 / 4) *(uint4*)&deg[i * 4] = make_uint4(0u, 0u, 0u, 0u);
}

// CSR build step 1: degree histogram over dst; atomic return value IS the rank
__global__ __launch_bounds__(256) void hist_kernel(
    const int* __restrict__ dst, int* __restrict__ deg, int* __restrict__ rank) {
  int e = blockIdx.x * 256 + threadIdx.x;
  if (e < N_EDGES) rank[e] = atomicAdd(&deg[dst[e]], 1);
}

// CSR build step 2a: per-chunk sums + dinv (fused; both read deg)
__global__ __launch_bounds__(SCAN_B) void scan_partial_kernel(
    const int* __restrict__ deg, int* __restrict__ bsums, float* __restrict__ dinv) {
  __shared__ int sh[SCAN_B];
  int t = threadIdx.x;
  int g = blockIdx.x * SCAN_B + t;
  int v = (g < N_NODES) ? deg[g] : 0;
  sh[t] = v;
  if (g < N_NODES) dinv[g] = rsqrtf((float)v + 1.0f);
  __syncthreads();
  for (int off = SCAN_B / 2; off > 0; off >>= 1) {
    if (t < off) sh[t] += sh[t + off];
    __syncthreads();
  }
  if (t == 0) bsums[blockIdx.x] = sh[0];
}

// CSR build step 2b: exclusive scan of the (tiny) chunk sums
__global__ __launch_bounds__(64) void scan_bsums_kernel(
    int* __restrict__ bsums, int* __restrict__ row_ptr) {
  __shared__ int sh[NB];
  int t = threadIdx.x;
  if (t < NB) sh[t] = bsums[t];
  __syncthreads();
  if (t == 0) {
    int acc = 0;
    for (int b = 0; b < NB; ++b) { int v = sh[b]; sh[b] = acc; acc += v; }
    row_ptr[N_NODES] = acc;  // == N_EDGES
  }
  __syncthreads();
  if (t < NB) bsums[t] = sh[t];
}

// CSR build step 2c: per-chunk exclusive scan + offset -> row_ptr
__global__ __launch_bounds__(SCAN_B) void scan_final_kernel(
    const int* __restrict__ deg, const int* __restrict__ bsums,
    int* __restrict__ row_ptr) {
  __shared__ int sh[SCAN_B];
  int t = threadIdx.x;
  int g = blockIdx.x * SCAN_B + t;
  int v = (g < N_NODES) ? deg[g] : 0;
  sh[t] = v;
  __syncthreads();
  for (int off = 1; off < SCAN_B; off <<= 1) {
    int add = (t >= off) ? sh[t - off] : 0;
    __syncthreads();
    sh[t] += add;
    __syncthreads();
  }
  int excl = sh[t] - v + bsums[blockIdx.x];
  if (g < N_NODES) row_ptr[g] = excl;
}

// CSR build step 3: place src ids (atomic-free; rank precomputed in hist)
__global__ __launch_bounds__(256) void place_kernel(
    const int* __restrict__ src, const int* __restrict__ dst,
    const int* __restrict__ rank, const int* __restrict__ row_ptr,
    int* __restrict__ csr_src) {
  int e = blockIdx.x * 256 + threadIdx.x;
  if (e < N_EDGES) {
    csr_src[row_ptr[dst[e]] + rank[e]] = src[e];
  }
}

// ---------------------------------------------------------------------------
// Both weights: W [128][C] fp32 -> Wt [C][128] bf16 (transpose + convert)
__global__ __launch_bounds__(256) void cvt_w_kernel(
    const float* __restrict__ W1, const float* __restrict__ W2,
    unsigned short* __restrict__ Wt1, unsigned short* __restrict__ Wt2) {
  int idx = blockIdx.x * 256 + threadIdx.x;
  if (idx < 128 * 128) {
    int k = idx >> 7, c = idx & 127;
    Wt1[c * 128 + k] = (unsigned short)bf16rne(W1[idx]);
  } else if (idx < 128 * 128 + 128 * 64) {
    int i = idx - 128 * 128;
    int k = i >> 6, c = i & 63;
    Wt2[c * 128 + k] = (unsigned short)bf16rne(W2[i]);
  }
}

// ---------------------------------------------------------------------------
// MFMA GEMM: out[nrows x N] bf16 = A[nrows x 128] @ Bt^T, Bt = [N][128] bf16.
// A is fp32 (AFP32=true, converted during LDS staging) or bf16.
template <int N, bool AFP32>
__global__ __launch_bounds__(256) void gemm_mfma_kernel(
    const void* __restrict__ Av, const unsigned short* __restrict__ Bt,
    unsigned short* __restrict__ out, int nrows) {
  constexpr int KP = 136;
  __shared__ unsigned short sA[64 * KP];
  __shared__ unsigned short sB[N * KP];

  const int row0 = blockIdx.x * 64;
  const int t = threadIdx.x;

  for (int i = t; i < 64 * 16; i += 256) {
    int r = i >> 4, ch = i & 15;
    uint4 v = make_uint4(0u, 0u, 0u, 0u);
    if (row0 + r < nrows) {
      if constexpr (AFP32) {
        const float* A = (const float*)Av;
        float4 f0 = *(const float4*)&A[(long)(row0 + r) * 128 + ch * 8];
        float4 f1 = *(const float4*)&A[(long)(row0 + r) * 128 + ch * 8 + 4];
        v.x = pack2bf(f0.x, f0.y); v.y = pack2bf(f0.z, f0.w);
        v.z = pack2bf(f1.x, f1.y); v.w = pack2bf(f1.z, f1.w);
      } else {
        const unsigned short* A = (const unsigned short*)Av;
        v = *(const uint4*)&A[(long)(row0 + r) * 128 + ch * 8];
      }
    }
    *(uint4*)&sA[r * KP + ch * 8] = v;
  }
  for (int i = t; i < N * 16; i += 256) {
    int r = i >> 4, ch = i & 15;
    *(uint4*)&sB[r * KP + ch * 8] = *(const uint4*)&Bt[(long)r * 128 + ch * 8];
  }
  __syncthreads();

  const int wave = t >> 6, lane = t & 63;
  const int m0 = wave * 16;
  const int lr = lane & 15;
  const int kg = lane >> 4;

  constexpr int NT = N / 16;
  v4f acc[NT];
#pragma unroll
  for (int i = 0; i < NT; ++i) acc[i] = (v4f)(0.f);

#pragma unroll
  for (int ks = 0; ks < 4; ++ks) {
    const int k0 = ks * 32 + kg * 8;
    v8s a = *(const v8s*)&sA[(m0 + lr) * KP + k0];
#pragma unroll
    for (int nt = 0; nt < NT; ++nt) {
      v8s b = *(const v8s*)&sB[(nt * 16 + lr) * KP + k0];
      acc[nt] = __builtin_amdgcn_mfma_f32_16x16x32_bf16(a, b, acc[nt], 0, 0, 0);
    }
  }

#pragma unroll
  for (int nt = 0; nt < NT; ++nt) {
#pragma unroll
    for (int i = 0; i < 4; ++i) {
      int gr = row0 + m0 + kg * 4 + i;
      if (gr < nrows)
        out[(long)gr * N + nt * 16 + lr] = (unsigned short)bf16rne(acc[nt][i]);
    }
  }
}

// ---------------------------------------------------------------------------
// Gather aggregation, one wave per node, 2 edges per VMEM instruction:
// lanes 0-31 own even edge of a pair, lanes 32-63 the odd edge.
// Invalid slots (past degree) re-load the last edge with weight 0.
// C=128: lane handles 4 channels (uint2 = 4 bf16). h1 output bf16 packed.
__global__ __launch_bounds__(256) void agg128_kernel(
    const int* __restrict__ row_ptr, const int* __restrict__ csr_src,
    const float* __restrict__ dinv, const unsigned* __restrict__ hw,  // [N][64] u32
    const float* __restrict__ bias, unsigned* __restrict__ h1out) {   // [N][64] u32
  int n = (blockIdx.x * 256 + threadIdx.x) >> 6;
  int lane = threadIdx.x & 63;
  if (n >= N_NODES) return;
  const int half = lane >> 5;      // which edge of the pair
  const int lc = lane & 31;        // channel quad: ch 4lc..4lc+3
  const int start = row_ptr[n];
  const int deg = row_ptr[n + 1] - start;
  const int np = (deg + 1) >> 1;   // pairs (last may be half-valid)

  float a0 = 0.f, a1 = 0.f, a2 = 0.f, a3 = 0.f;

#define LS(i, pp) { int tt = 2 * (pp) + half; int cl = tt < deg ? tt : deg - 1; \
                    s##i = csr_src[start + cl]; m##i = (tt < deg) ? 1.f : 0.f; }
  int s0, s1, s2, s3;
  float m0, m1, m2, m3;
  if (np > 0) { LS(0, 0) LS(1, 1) LS(2, 2) LS(3, 3) }
  for (int p = 0; p < np; p += 4) {
    int q0 = s0, q1 = s1, q2 = s2, q3 = s3;
    float f0 = m0, f1 = m1, f2 = m2, f3 = m3;
    int pn = p + 4;
    if (pn < np) { LS(0, pn) LS(1, pn + 1) LS(2, pn + 2) LS(3, pn + 3) }
    float w0 = dinv[q0] * f0;
    float w1 = dinv[q1] * f1;
    float w2 = dinv[q2] * f2;
    float w3 = dinv[q3] * f3;
    uint2 u0 = *(const uint2*)&hw[(long)q0 * 64 + 2 * lc];
    uint2 u1 = *(const uint2*)&hw[(long)q1 * 64 + 2 * lc];
    uint2 u2 = *(const uint2*)&hw[(long)q2 * 64 + 2 * lc];
    uint2 u3 = *(const uint2*)&hw[(long)q3 * 64 + 2 * lc];
    a0 = fmaf(bflo_to_f(u0.x), w0, a0); a1 = fmaf(bfhi_to_f(u0.x), w0, a1);
    a2 = fmaf(bflo_to_f(u0.y), w0, a2); a3 = fmaf(bfhi_to_f(u0.y), w0, a3);
    a0 = fmaf(bflo_to_f(u1.x), w1, a0); a1 = fmaf(bfhi_to_f(u1.x), w1, a1);
    a2 = fmaf(bflo_to_f(u1.y), w1, a2); a3 = fmaf(bfhi_to_f(u1.y), w1, a3);
    a0 = fmaf(bflo_to_f(u2.x), w2, a0); a1 = fmaf(bfhi_to_f(u2.x), w2, a1);
    a2 = fmaf(bflo_to_f(u2.y), w2, a2); a3 = fmaf(bfhi_to_f(u2.y), w2, a3);
    a0 = fmaf(bflo_to_f(u3.x), w3, a0); a1 = fmaf(bfhi_to_f(u3.x), w3, a1);
    a2 = fmaf(bflo_to_f(u3.y), w3, a2); a3 = fmaf(bfhi_to_f(u3.y), w3, a3);
  }
#undef LS

  // combine the two half-wave partial sums (lane l <-> l^32)
  a0 += __shfl_xor(a0, 32);
  a1 += __shfl_xor(a1, 32);
  a2 += __shfl_xor(a2, 32);
  a3 += __shfl_xor(a3, 32);

  float dn = dinv[n];
  float sn = dn * dn;
  uint2 uh = *(const uint2*)&hw[(long)n * 64 + 2 * lc];
  float4 bb = *(const float4*)&bias[4 * lc];
  float o0 = fmaxf(fmaf(bflo_to_f(uh.x), sn, a0 * dn) + bb.x, 0.f);
  float o1 = fmaxf(fmaf(bfhi_to_f(uh.x), sn, a1 * dn) + bb.y, 0.f);
  float o2 = fmaxf(fmaf(bflo_to_f(uh.y), sn, a2 * dn) + bb.z, 0.f);
  float o3 = fmaxf(fmaf(bfhi_to_f(uh.y), sn, a3 * dn) + bb.w, 0.f);
  if (half == 0) {
    uint2 pz;
    pz.x = pack2bf(o0, o1);
    pz.y = pack2bf(o2, o3);
    *(uint2*)&h1out[(long)n * 64 + 2 * lc] = pz;
  }
}

// C=64: lane handles 2 channels (u32 = 2 bf16); fp32 output (final).
__global__ __launch_bounds__(256) void agg64_kernel(
    const int* __restrict__ row_ptr, const int* __restrict__ csr_src,
    const float* __restrict__ dinv, const unsigned* __restrict__ hw,  // [N][32] u32
    const float* __restrict__ bias, float* __restrict__ out) {
  int n = (blockIdx.x * 256 + threadIdx.x) >> 6;
  int lane = threadIdx.x & 63;
  if (n >= N_NODES) return;
  const int half = lane >> 5;
  const int lc = lane & 31;        // channel pair: ch 2lc, 2lc+1
  const int start = row_ptr[n];
  const int deg = row_ptr[n + 1] - start;
  const int np = (deg + 1) >> 1;

  float a0 = 0.f, a1 = 0.f;

#define LS(i, pp) { int tt = 2 * (pp) + half; int cl = tt < deg ? tt : deg - 1; \
                    s##i = csr_src[start + cl]; m##i = (tt < deg) ? 1.f : 0.f; }
  int s0, s1, s2, s3;
  float m0, m1, m2, m3;
  if (np > 0) { LS(0, 0) LS(1, 1) LS(2, 2) LS(3, 3) }
  for (int p = 0; p < np; p += 4) {
    int q0 = s0, q1 = s1, q2 = s2, q3 = s3;
    float f0 = m0, f1 = m1, f2 = m2, f3 = m3;
    int pn = p + 4;
    if (pn < np) { LS(0, pn) LS(1, pn + 1) LS(2, pn + 2) LS(3, pn + 3) }
    float w0 = dinv[q0] * f0;
    float w1 = dinv[q1] * f1;
    float w2 = dinv[q2] * f2;
    float w3 = dinv[q3] * f3;
    unsigned u0 = hw[(long)q0 * 32 + lc];
    unsigned u1 = hw[(long)q1 * 32 + lc];
    unsigned u2 = hw[(long)q2 * 32 + lc];
    unsigned u3 = hw[(long)q3 * 32 + lc];
    a0 = fmaf(bflo_to_f(u0), w0, a0); a1 = fmaf(bfhi_to_f(u0), w0, a1);
    a0 = fmaf(bflo_to_f(u1), w1, a0); a1 = fmaf(bfhi_to_f(u1), w1, a1);
    a0 = fmaf(bflo_to_f(u2), w2, a0); a1 = fmaf(bfhi_to_f(u2), w2, a1);
    a0 = fmaf(bflo_to_f(u3), w3, a0); a1 = fmaf(bfhi_to_f(u3), w3, a1);
  }
#undef LS

  a0 += __shfl_xor(a0, 32);
  a1 += __shfl_xor(a1, 32);

  float dn = dinv[n];
  float sn = dn * dn;
  unsigned uh = hw[(long)n * 32 + lc];
  float2 bb = *(const float2*)&bias[2 * lc];
  float o0 = fmaxf(fmaf(bflo_to_f(uh), sn, a0 * dn) + bb.x, 0.f);
  float o1 = fmaxf(fmaf(bfhi_to_f(uh), sn, a1 * dn) + bb.y, 0.f);
  if (half == 0) {
    *(float2*)&out[(long)n * 64 + 2 * lc] = make_float2(o0, o1);
  }
}

// ---------------------------------------------------------------------------
extern "C" void kernel_launch(void* const* d_in, const int* in_sizes, int n_in,
                              void* d_out, int out_size, void* d_ws, size_t ws_size,
                              hipStream_t stream) {
  const float* x  = (const float*)d_in[0];
  const int*   ei = (const int*)d_in[1];
  const float* W1 = (const float*)d_in[2];
  const float* b1 = (const float*)d_in[3];
  const float* W2 = (const float*)d_in[4];
  const float* b2 = (const float*)d_in[5];
  float* out = (float*)d_out;

  const int* src = ei;             // edge_index[0]
  const int* dst = ei + N_EDGES;   // edge_index[1]

  // Workspace layout (bytes; every chunk is a multiple of 256B)
  char* ws = (char*)d_ws;
  int*   deg     = (int*)ws;                     ws += 50048 * 4;
  float* dinv    = (float*)ws;                   ws += 50048 * 4;
  int*   row_ptr = (int*)ws;                     ws += 50048 * 4;
  int*   bsums   = (int*)ws;                     ws += 64 * 4;
  int*   rank    = (int*)ws;                     ws += (size_t)N_EDGES * 4;
  int*   csr_src = (int*)ws;                     ws += (size_t)N_EDGES * 4;
  unsigned short* Wt1 = (unsigned short*)ws;     ws += 128 * 128 * 2;
  unsigned short* Wt2 = (unsigned short*)ws;     ws += 64 * 128 * 2;
  unsigned short* hw1 = (unsigned short*)ws;     ws += (size_t)N_NODES * 128 * 2;
  unsigned*       h1  = (unsigned*)ws;           ws += (size_t)N_NODES * 64 * 4;
  unsigned short* hw2 = (unsigned short*)ws;     ws += (size_t)N_NODES * 64 * 2;

  // ---- CSR build ----
  zero_deg_kernel<<<49, 256, 0, stream>>>(deg);
  hist_kernel<<<(N_EDGES + 255) / 256, 256, 0, stream>>>(dst, deg, rank);
  scan_partial_kernel<<<NB, SCAN_B, 0, stream>>>(deg, bsums, dinv);
  scan_bsums_kernel<<<1, 64, 0, stream>>>(bsums, row_ptr);
  scan_final_kernel<<<NB, SCAN_B, 0, stream>>>(deg, bsums, row_ptr);
  place_kernel<<<(N_EDGES + 255) / 256, 256, 0, stream>>>(src, dst, rank, row_ptr, csr_src);

  // ---- Weight conversions (tiny) ----
  cvt_w_kernel<<<96, 256, 0, stream>>>(W1, W2, Wt1, Wt2);

  // ---- Layer 1 (x converted to bf16 inside GEMM staging) ----
  gemm_mfma_kernel<128, true><<<(N_NODES + 63) / 64, 256, 0, stream>>>(
      x, Wt1, hw1, N_NODES);
  agg128_kernel<<<(N_NODES * 64 + 255) / 256, 256, 0, stream>>>(
      row_ptr, csr_src, dinv, (const unsigned*)hw1, b1, h1);

  // ---- Layer 2 ----
  gemm_mfma_kernel<64, false><<<(N_NODES + 63) / 64, 256, 0, stream>>>(
      h1, Wt2, hw2, N_NODES);
  agg64_kernel<<<(N_NODES * 64 + 255) / 256, 256, 0, stream>>>(
      row_ptr, csr_src, dinv, (const unsigned*)hw2, b2, out);
}